// Round 6
// baseline (800.805 us; speedup 1.0000x reference)
//
#include <hip/hip_runtime.h>
#include <hip/hip_bf16.h>
#include <cstddef>

typedef short bf16x8 __attribute__((ext_vector_type(8)));
typedef float f32x4 __attribute__((ext_vector_type(4)));

__device__ __forceinline__ unsigned short f2bf(float x) {
  __hip_bfloat16 h = __float2bfloat16(x);
  unsigned short u; __builtin_memcpy(&u, &h, 2); return u;
}
__device__ __forceinline__ float swz16f(float x) {   // lane ^= 16 (within 32-group)
  int i; __builtin_memcpy(&i, &x, 4);
  i = __builtin_amdgcn_ds_swizzle(i, 0x401F);
  float r; __builtin_memcpy(&r, &i, 4); return r;
}
template<int PAT>
__device__ __forceinline__ float swzp(float x) {
  int i; __builtin_memcpy(&i, &x, 4);
  i = __builtin_amdgcn_ds_swizzle(i, PAT);
  float r; __builtin_memcpy(&r, &i, 4); return r;
}
__device__ __forceinline__ void gload16(const unsigned short* g, unsigned short* l) {
  __builtin_amdgcn_global_load_lds(
      (const __attribute__((address_space(1))) void*)g,
      (__attribute__((address_space(3))) void*)l, 16, 0, 0);
}

// ---------------- weight fp32 -> bf16 convert ----------------
__global__ __launch_bounds__(256) void f2bf_kernel(
    const float* __restrict__ src, unsigned short* __restrict__ dst, int n4)
{
  int i = blockIdx.x * 256 + threadIdx.x;
  if (i < n4) {
    float4 v = *(const float4*)(src + (size_t)i * 4);
    ushort4 o;
    o.x = f2bf(v.x); o.y = f2bf(v.y); o.z = f2bf(v.z); o.w = f2bf(v.w);
    *(ushort4*)(dst + (size_t)i * 4) = o;
  }
}

// ---------------- conv1d (circular, k=3) + positional embedding ----------------
__global__ __launch_bounds__(256) void conv_pe_kernel(
    const float* __restrict__ x, const float* __restrict__ cw,
    const float* __restrict__ cb,
    float* __restrict__ outf, unsigned short* __restrict__ outb)
{
  const int L = 2048, CIN = 32;
  int b  = blockIdx.x >> 8;
  int l0 = (blockIdx.x & 255) << 3;
  int t  = threadIdx.x;
  __shared__ float xs[10][32];
  for (int idx = t; idx < 320; idx += 256) {
    int rr = idx >> 5, ci = idx & 31;
    int gl = (l0 - 1 + rr + L) & (L - 1);
    xs[rr][ci] = x[((size_t)b * L + gl) * CIN + ci];
  }
  __syncthreads();
  int e0 = t << 1;
  float acc0[8], acc1[8];
  float bb0 = cb[e0], bb1 = cb[e0 + 1];
#pragma unroll
  for (int li = 0; li < 8; li++) { acc0[li] = bb0; acc1[li] = bb1; }
  const float* w0p = cw + (size_t)e0 * 96;
  const float* w1p = w0p + 96;
  for (int ci = 0; ci < 32; ci++) {
#pragma unroll
    for (int kk = 0; kk < 3; kk++) {
      float w0 = w0p[ci * 3 + kk];
      float w1 = w1p[ci * 3 + kk];
#pragma unroll
      for (int li = 0; li < 8; li++) {
        float xv = xs[li + kk][ci];
        acc0[li] += xv * w0;
        acc1[li] += xv * w1;
      }
    }
  }
  float dv = __expf((float)e0 * (-9.210340371976184f / 512.0f));
#pragma unroll
  for (int li = 0; li < 8; li++) {
    int l = l0 + li;
    float arg = (float)l * dv;
    float sv = sinf(arg), cv = cosf(arg);
    float2 o; o.x = acc0[li] + sv; o.y = acc1[li] + cv;
    size_t off = ((size_t)b * L + l) * 512 + e0;
    *(float2*)&outf[off] = o;
    ushort2 ob; ob.x = f2bf(o.x); ob.y = f2bf(o.y);
    *(ushort2*)&outb[off] = ob;
  }
}

// ---------------- bf16 MFMA GEMM (qkv): Y = X @ W^T + bias, Q cols prescaled ----
template<int EPI, int QSCALE>
__global__ __launch_bounds__(256) void gemm_bf(
    const unsigned short* __restrict__ X,
    const unsigned short* __restrict__ W,
    const float* __restrict__ bias,
    const float* __restrict__ R,
    unsigned short* __restrict__ Yb,
    float* __restrict__ Yf,
    int N)
{
  const int K = 512;
  __shared__ unsigned short Xs[128 * 64];
  __shared__ unsigned short Ws[128 * 64];
  int t = threadIdx.x;
  int lane = t & 63, wv = t >> 6;
  int g = lane >> 4, li = lane & 15;
  int m0 = (blockIdx.x & 63) << 7;
  int n0 = (blockIdx.x >> 6) << 7;
  int wm = (wv >> 1) << 6, wn = (wv & 1) << 6;

  int subrow = lane >> 3;
  int coloff = ((lane & 7) ^ subrow) << 3;

  f32x4 acc[4][4];
#pragma unroll
  for (int a = 0; a < 4; a++)
#pragma unroll
    for (int b2 = 0; b2 < 4; b2++) acc[a][b2] = (f32x4){0.f, 0.f, 0.f, 0.f};

  for (int k0 = 0; k0 < K; k0 += 64) {
    __syncthreads();
#pragma unroll
    for (int j = 0; j < 4; j++) {
      int row = (wv * 4 + j) * 8 + subrow;
      gload16(X + (size_t)(m0 + row) * K + k0 + coloff, Xs + (wv * 4 + j) * 512);
      gload16(W + (size_t)(n0 + row) * K + k0 + coloff, Ws + (wv * 4 + j) * 512);
    }
    __syncthreads();
#pragma unroll
    for (int s = 0; s < 2; s++) {
      bf16x8 af[4], bfr[4];
#pragma unroll
      for (int mt = 0; mt < 4; mt++) {
        int row = wm + 16 * mt + li;
        af[mt] = ((const bf16x8*)Xs)[row * 8 + ((g + 4 * s) ^ (row & 7))];
      }
#pragma unroll
      for (int nt = 0; nt < 4; nt++) {
        int row = wn + 16 * nt + li;
        bfr[nt] = ((const bf16x8*)Ws)[row * 8 + ((g + 4 * s) ^ (row & 7))];
      }
#pragma unroll
      for (int mt = 0; mt < 4; mt++)
#pragma unroll
        for (int nt = 0; nt < 4; nt++)
          acc[mt][nt] = __builtin_amdgcn_mfma_f32_16x16x32_bf16(
              af[mt], bfr[nt], acc[mt][nt], 0, 0, 0);
    }
  }
  float bv[4];
#pragma unroll
  for (int nt = 0; nt < 4; nt++) bv[nt] = bias[n0 + wn + 16 * nt + li];
#pragma unroll
  for (int mt = 0; mt < 4; mt++) {
#pragma unroll
    for (int i = 0; i < 4; i++) {
      size_t roff = (size_t)(m0 + wm + 16 * mt + 4 * g + i) * N;
#pragma unroll
      for (int nt = 0; nt < 4; nt++) {
        int col = n0 + wn + 16 * nt + li;
        float v = acc[mt][nt][i] + bv[nt];
        if (EPI == 1) {
          v += R[roff + col];
          Yf[roff + col] = v;
        } else {
          if (QSCALE && col < 512) v *= 0.18033688011112042f;  // 0.125*log2(e)
          Yb[roff + col] = f2bf(v);
        }
      }
    }
  }
}

// ---------------- V transpose: qkv_bf V-part -> Vt[32][64][2048] ----------------
__global__ __launch_bounds__(256) void vtrans_kernel(
    const unsigned short* __restrict__ qkv, unsigned short* __restrict__ Vt)
{
  int ki = blockIdx.x & 31, bh = blockIdx.x >> 5;
  int b = bh >> 3, h = bh & 7;
  int kt = ki << 6;
  __shared__ unsigned short T[64][72];
  int t = threadIdx.x;
  int r = t >> 2, c0 = (t & 3) << 4;
  const unsigned short* src =
      qkv + ((size_t)(b * 2048 + kt + r)) * 1536 + 1024 + h * 64 + c0;
  bf16x8 a0 = *(const bf16x8*)src;
  bf16x8 a1 = *(const bf16x8*)(src + 8);
  *(bf16x8*)&T[r][c0] = a0;
  *(bf16x8*)&T[r][c0 + 8] = a1;
  __syncthreads();
  int d = t >> 2, k0 = (t & 3) << 4;
  bf16x8 v0, v1;
#pragma unroll
  for (int j = 0; j < 8; j++) v0[j] = (short)T[k0 + j][d];
#pragma unroll
  for (int j = 0; j < 8; j++) v1[j] = (short)T[k0 + 8 + j][d];
  unsigned short* dst = Vt + ((size_t)bh * 64 + d) * 2048 + kt + k0;
  *(bf16x8*)dst = v0;
  *(bf16x8*)(dst + 8) = v1;
}

// ---------------- MFMA flash attention: QBLK=128, 2 q-frags per wave ----------
// grid: 16 q-tiles x 32 bh; 256 thr = 4 waves; 64-key tiles; Q prescaled.
__global__ __launch_bounds__(256) void attn_mfma(
    const unsigned short* __restrict__ qkv,  // [8192,1536] bf16
    const unsigned short* __restrict__ Vt,   // [32,64,2048] bf16
    unsigned short* __restrict__ ctx)        // [8192,512] bf16
{
  const int L = 2048;
  int qi = blockIdx.x & 15, bh = blockIdx.x >> 4;
  int b = bh >> 3, h = bh & 7;
  int q0 = qi << 7;
  size_t tb = (size_t)b * L;
  int t = threadIdx.x, lane = t & 63, wv = t >> 6;
  int g = lane >> 4, li = lane & 15;
  int lisw = li & 7;

  // smem carve: Ks [0,8K) | Vs [8K,16K) | Ps [16K,32K) (4KB per wave)
  __shared__ __align__(16) char smem[32768];

  int wq = q0 + wv * 32;
  bf16x8 qf00, qf01, qf10, qf11;
  {
    const unsigned short* qp0 = qkv + (tb + wq + li) * 1536 + h * 64 + g * 8;
    qf00 = *(const bf16x8*)qp0;
    qf01 = *(const bf16x8*)(qp0 + 32);
    const unsigned short* qp1 = qp0 + (size_t)16 * 1536;
    qf10 = *(const bf16x8*)qp1;
    qf11 = *(const bf16x8*)(qp1 + 32);
  }

  f32x4 accA[4], accB[4];
#pragma unroll
  for (int nt = 0; nt < 4; nt++) {
    accA[nt] = (f32x4){0.f, 0.f, 0.f, 0.f};
    accB[nt] = (f32x4){0.f, 0.f, 0.f, 0.f};
  }
  float mA = -1e30f, mB = -1e30f, lA = 0.f, lB = 0.f;

  // hoisted LDS bases (compile-time offsets do the rest)
  const char* kv0 = smem + li * 128 + ((g    ) ^ lisw) * 16;
  const char* kv1 = smem + li * 128 + ((g + 4) ^ lisw) * 16;
  const char* pb0 = smem + 16384 + wv * 4096 + li * 128 + ((g    ) ^ lisw) * 16;
  const char* pb1 = smem + 16384 + wv * 4096 + li * 128 + ((g + 4) ^ lisw) * 16;
  char* pwbase = smem + 16384 + wv * 4096 + li * 128 + ((g & 1) << 3);
  char* pw0 = pwbase + (((0 + (g >> 1)) ^ lisw) << 4);
  char* pw1 = pwbase + (((2 + (g >> 1)) ^ lisw) << 4);
  char* pw2 = pwbase + (((4 + (g >> 1)) ^ lisw) << 4);
  char* pw3 = pwbase + (((6 + (g >> 1)) ^ lisw) << 4);

  // staging pointers (incremented per tile)
  int subrow = lane >> 3;
  int coloff = ((lane & 7) ^ subrow) << 3;
  int r0 = wv * 16 + subrow, r1 = wv * 16 + 8 + subrow;
  const unsigned short* kp0 = qkv + (tb + r0) * 1536 + 512 + h * 64 + coloff;
  const unsigned short* kp1 = qkv + (tb + r1) * 1536 + 512 + h * 64 + coloff;
  const unsigned short* vp0 = Vt + ((size_t)bh * 64 + r0) * 2048 + coloff;
  const unsigned short* vp1 = Vt + ((size_t)bh * 64 + r1) * 2048 + coloff;
  unsigned short* dK0 = (unsigned short*)smem + (wv * 2) * 512;
  unsigned short* dK1 = dK0 + 512;
  unsigned short* dV0 = (unsigned short*)(smem + 8192) + (wv * 2) * 512;
  unsigned short* dV1 = dV0 + 512;

  for (int kt = 0; kt < L; kt += 64) {
    __syncthreads();
    gload16(kp0, dK0); gload16(kp1, dK1);
    gload16(vp0, dV0); gload16(vp1, dV1);
    kp0 += (size_t)64 * 1536; kp1 += (size_t)64 * 1536;
    vp0 += 64; vp1 += 64;
    __syncthreads();

    // S^T = K . Q^T  (kf shared across both q-frags)
    f32x4 sA[4], sB[4];
#pragma unroll
    for (int mt = 0; mt < 4; mt++) {
      sA[mt] = (f32x4){0.f, 0.f, 0.f, 0.f};
      sB[mt] = (f32x4){0.f, 0.f, 0.f, 0.f};
    }
#pragma unroll
    for (int mt = 0; mt < 4; mt++) {
      bf16x8 kf = *(const bf16x8*)(kv0 + mt * 2048);
      sA[mt] = __builtin_amdgcn_mfma_f32_16x16x32_bf16(kf, qf00, sA[mt], 0, 0, 0);
      sB[mt] = __builtin_amdgcn_mfma_f32_16x16x32_bf16(kf, qf10, sB[mt], 0, 0, 0);
    }
#pragma unroll
    for (int mt = 0; mt < 4; mt++) {
      bf16x8 kf = *(const bf16x8*)(kv1 + mt * 2048);
      sA[mt] = __builtin_amdgcn_mfma_f32_16x16x32_bf16(kf, qf01, sA[mt], 0, 0, 0);
      sB[mt] = __builtin_amdgcn_mfma_f32_16x16x32_bf16(kf, qf11, sB[mt], 0, 0, 0);
    }

    // tile maxes (lane owns q=li per frag)
    float mxA, mxB;
    {
      float a0 = fmaxf(fmaxf(sA[0][0], sA[0][1]), fmaxf(sA[0][2], sA[0][3]));
      float a1 = fmaxf(fmaxf(sA[1][0], sA[1][1]), fmaxf(sA[1][2], sA[1][3]));
      float a2 = fmaxf(fmaxf(sA[2][0], sA[2][1]), fmaxf(sA[2][2], sA[2][3]));
      float a3 = fmaxf(fmaxf(sA[3][0], sA[3][1]), fmaxf(sA[3][2], sA[3][3]));
      mxA = fmaxf(fmaxf(a0, a1), fmaxf(a2, a3));
      float b0 = fmaxf(fmaxf(sB[0][0], sB[0][1]), fmaxf(sB[0][2], sB[0][3]));
      float b1 = fmaxf(fmaxf(sB[1][0], sB[1][1]), fmaxf(sB[1][2], sB[1][3]));
      float b2 = fmaxf(fmaxf(sB[2][0], sB[2][1]), fmaxf(sB[2][2], sB[2][3]));
      float b3 = fmaxf(fmaxf(sB[3][0], sB[3][1]), fmaxf(sB[3][2], sB[3][3]));
      mxB = fmaxf(fmaxf(b0, b1), fmaxf(b2, b3));
    }
    mxA = fmaxf(mxA, swz16f(mxA)); mxA = fmaxf(mxA, __shfl_xor(mxA, 32));
    mxB = fmaxf(mxB, swz16f(mxB)); mxB = fmaxf(mxB, __shfl_xor(mxB, 32));

    // defer-max (THR=8, exp2 domain)
    if (__any((mxA > mA + 8.0f) || (mxB > mB + 8.0f))) {
      float mnA = fmaxf(mA, mxA), mnB = fmaxf(mB, mxB);
      float cA = mA - mnA, cB = mB - mnB;
      asm volatile("v_exp_f32 %0, %0\n\tv_exp_f32 %1, %1\n\ts_nop 1"
                   : "+v"(cA), "+v"(cB));
      float c0 = __shfl(cA, 4 * g + 0), c1 = __shfl(cA, 4 * g + 1);
      float c2 = __shfl(cA, 4 * g + 2), c3 = __shfl(cA, 4 * g + 3);
#pragma unroll
      for (int nt = 0; nt < 4; nt++) {
        accA[nt][0] *= c0; accA[nt][1] *= c1;
        accA[nt][2] *= c2; accA[nt][3] *= c3;
      }
      float d0 = __shfl(cB, 4 * g + 0), d1 = __shfl(cB, 4 * g + 1);
      float d2 = __shfl(cB, 4 * g + 2), d3 = __shfl(cB, 4 * g + 3);
#pragma unroll
      for (int nt = 0; nt < 4; nt++) {
        accB[nt][0] *= d0; accB[nt][1] *= d1;
        accB[nt][2] *= d2; accB[nt][3] *= d3;
      }
      lA *= cA; lB *= cB;
      mA = mnA; mB = mnB;
    }

    // p = 2^(s-m), sum, cvt_pk, LDS write — per-mt to bound register lifetime
    float psA = 0.f, psB = 0.f;
#define PBLK(SARR, MM, PS, PWP, OFF)                                          \
    {                                                                         \
      float p0 = SARR[0] - MM, p1 = SARR[1] - MM,                             \
            p2 = SARR[2] - MM, p3 = SARR[3] - MM;                             \
      asm volatile("v_exp_f32 %0, %0\n\tv_exp_f32 %1, %1\n\t"                 \
                   "v_exp_f32 %2, %2\n\tv_exp_f32 %3, %3\n\ts_nop 1"          \
                   : "+v"(p0), "+v"(p1), "+v"(p2), "+v"(p3));                 \
      PS += (p0 + p1) + (p2 + p3);                                            \
      uint2 pv;                                                               \
      asm("v_cvt_pk_bf16_f32 %0, %1, %2" : "=v"(pv.x) : "v"(p0), "v"(p1));    \
      asm("v_cvt_pk_bf16_f32 %0, %1, %2" : "=v"(pv.y) : "v"(p2), "v"(p3));    \
      *(uint2*)(PWP + OFF) = pv;                                              \
    }
    PBLK(sA[0], mA, psA, pw0, 0) PBLK(sA[1], mA, psA, pw1, 0)
    PBLK(sA[2], mA, psA, pw2, 0) PBLK(sA[3], mA, psA, pw3, 0)
    PBLK(sB[0], mB, psB, pw0, 2048) PBLK(sB[1], mB, psB, pw1, 2048)
    PBLK(sB[2], mB, psB, pw2, 2048) PBLK(sB[3], mB, psB, pw3, 2048)
#undef PBLK
    psA += swz16f(psA); psA += __shfl_xor(psA, 32); lA += psA;
    psB += swz16f(psB); psB += __shfl_xor(psB, 32); lB += psB;

    // O += P . V  (vb shared across both frags)
    {
      bf16x8 paA0 = *(const bf16x8*)(pb0);
      bf16x8 paB0 = *(const bf16x8*)(pb0 + 2048);
#pragma unroll
      for (int nt = 0; nt < 4; nt++) {
        bf16x8 vb = *(const bf16x8*)(kv0 + 8192 + nt * 2048);
        accA[nt] = __builtin_amdgcn_mfma_f32_16x16x32_bf16(paA0, vb, accA[nt], 0, 0, 0);
        accB[nt] = __builtin_amdgcn_mfma_f32_16x16x32_bf16(paB0, vb, accB[nt], 0, 0, 0);
      }
      bf16x8 paA1 = *(const bf16x8*)(pb1);
      bf16x8 paB1 = *(const bf16x8*)(pb1 + 2048);
#pragma unroll
      for (int nt = 0; nt < 4; nt++) {
        bf16x8 vb = *(const bf16x8*)(kv1 + 8192 + nt * 2048);
        accA[nt] = __builtin_amdgcn_mfma_f32_16x16x32_bf16(paA1, vb, accA[nt], 0, 0, 0);
        accB[nt] = __builtin_amdgcn_mfma_f32_16x16x32_bf16(paB1, vb, accB[nt], 0, 0, 0);
      }
    }
  }

  float liA[4], liB[4];
#pragma unroll
  for (int i = 0; i < 4; i++) {
    liA[i] = 1.f / __shfl(lA, 4 * g + i);
    liB[i] = 1.f / __shfl(lB, 4 * g + i);
  }
#pragma unroll
  for (int i = 0; i < 4; i++) {
    size_t ra = (tb + wq + 4 * g + i) * 512 + h * 64;
    size_t rb = (tb + wq + 16 + 4 * g + i) * 512 + h * 64;
#pragma unroll
    for (int nt = 0; nt < 4; nt++) {
      ctx[ra + 16 * nt + li] = f2bf(accA[nt][i] * liA[i]);
      ctx[rb + 16 * nt + li] = f2bf(accB[nt][i] * liB[i]);
    }
  }
}

// ---------------- full-row GEMM (N=512,K=512) + fused epilogue ----------------
// DOLN=1: Y = LN(acc+bias+R) -> Yf f32 + Yb bf16.  DOLN=0: Y = SiLU -> Yb bf16.
// BM=32, BK=32, grid 256, 4 waves; wave owns cols wv*128..+127, rows all 32.
template<int DOLN>
__global__ __launch_bounds__(256) void gemm_ln(
    const unsigned short* __restrict__ X,
    const unsigned short* __restrict__ W,
    const float* __restrict__ bias,
    const float* __restrict__ R,
    const float* __restrict__ lnw,
    const float* __restrict__ lnb,
    float* __restrict__ Yf,
    unsigned short* __restrict__ Yb)
{
  const int K = 512;
  // smem: As [0,2048) | Ws [2048,34816) | red [34816,35840)
  __shared__ __align__(16) char smem[35840];
  int t = threadIdx.x, lane = t & 63, wv = t >> 6;
  int g = lane >> 4, li = lane & 15;
  int m0 = blockIdx.x << 5;

  int srow4 = lane >> 2;          // 0..15
  int scol  = (lane & 3) << 3;    // shorts (16B chunk)

  const unsigned short* Xg = X + (size_t)(m0 + wv * 16 + srow4) * K + scol;  // wv<2 only
  unsigned short* dA = (unsigned short*)smem + wv * 512;
  unsigned short* dW = (unsigned short*)(smem + 2048);

  const char* ab = smem + li * 64 + g * 16;
  const char* wb = smem + 2048 + wv * 8192 + li * 64 + g * 16;

  f32x4 acc0[8], acc1[8];
#pragma unroll
  for (int nt = 0; nt < 8; nt++) {
    acc0[nt] = (f32x4){0.f, 0.f, 0.f, 0.f};
    acc1[nt] = (f32x4){0.f, 0.f, 0.f, 0.f};
  }

  for (int k0 = 0; k0 < K; k0 += 32) {
    __syncthreads();
    if (wv < 2) gload16(Xg + k0, dA);
#pragma unroll
    for (int j = 0; j < 8; j++) {
      int n = wv * 128 + j * 16 + srow4;
      gload16(W + (size_t)n * K + k0 + scol, dW + (wv * 8 + j) * 512);
    }
    __syncthreads();
    bf16x8 af0 = *(const bf16x8*)(ab);
    bf16x8 af1 = *(const bf16x8*)(ab + 1024);
#pragma unroll
    for (int nt = 0; nt < 8; nt++) {
      bf16x8 bfv = *(const bf16x8*)(wb + nt * 1024);
      acc0[nt] = __builtin_amdgcn_mfma_f32_16x16x32_bf16(af0, bfv, acc0[nt], 0, 0, 0);
      acc1[nt] = __builtin_amdgcn_mfma_f32_16x16x32_bf16(af1, bfv, acc1[nt], 0, 0, 0);
    }
  }

  int colb = wv * 128 + li;
  float bv[8];
#pragma unroll
  for (int nt = 0; nt < 8; nt++) bv[nt] = bias[colb + nt * 16];

  // add bias (+ residual)
#pragma unroll
  for (int i = 0; i < 4; i++) {
    if (DOLN) {
      const float* Ra = R + (size_t)(m0 + 4 * g + i) * 512 + colb;
      const float* Rb = R + (size_t)(m0 + 16 + 4 * g + i) * 512 + colb;
#pragma unroll
      for (int nt = 0; nt < 8; nt++) {
        acc0[nt][i] += bv[nt] + Ra[nt * 16];
        acc1[nt][i] += bv[nt] + Rb[nt * 16];
      }
    } else {
#pragma unroll
      for (int nt = 0; nt < 8; nt++) {
        acc0[nt][i] += bv[nt];
        acc1[nt][i] += bv[nt];
      }
    }
  }

  if (DOLN) {
    float s1a[4], s2a[4], s1b[4], s2b[4];
#pragma unroll
    for (int i = 0; i < 4; i++) {
      float x1 = 0.f, x2 = 0.f, y1 = 0.f, y2 = 0.f;
#pragma unroll
      for (int nt = 0; nt < 8; nt++) {
        float va = acc0[nt][i], vb2 = acc1[nt][i];
        x1 += va; x2 += va * va;
        y1 += vb2; y2 += vb2 * vb2;
      }
      s1a[i] = x1; s2a[i] = x2; s1b[i] = y1; s2b[i] = y2;
    }
#pragma unroll
    for (int i = 0; i < 4; i++) {
      s1a[i] += swzp<0x041F>(s1a[i]); s2a[i] += swzp<0x041F>(s2a[i]);
      s1b[i] += swzp<0x041F>(s1b[i]); s2b[i] += swzp<0x041F>(s2b[i]);
      s1a[i] += swzp<0x081F>(s1a[i]); s2a[i] += swzp<0x081F>(s2a[i]);
      s1b[i] += swzp<0x081F>(s1b[i]); s2b[i] += swzp<0x081F>(s2b[i]);
      s1a[i] += swzp<0x101F>(s1a[i]); s2a[i] += swzp<0x101F>(s2a[i]);
      s1b[i] += swzp<0x101F>(s1b[i]); s2b[i] += swzp<0x101F>(s2b[i]);
      s1a[i] += swzp<0x201F>(s1a[i]); s2a[i] += swzp<0x201F>(s2a[i]);
      s1b[i] += swzp<0x201F>(s1b[i]); s2b[i] += swzp<0x201F>(s2b[i]);
    }
    float* red = (float*)(smem + 34816);
    if (li == 0) {
#pragma unroll
      for (int i = 0; i < 4; i++) {
        red[wv * 64 + 4 * g + i]      = s1a[i];
        red[wv * 64 + 16 + 4 * g + i] = s1b[i];
        red[wv * 64 + 32 + 4 * g + i] = s2a[i];
        red[wv * 64 + 48 + 4 * g + i] = s2b[i];
      }
    }
    __syncthreads();
    float gw[8], gbv[8];
#pragma unroll
    for (int nt = 0; nt < 8; nt++) {
      gw[nt] = lnw[colb + nt * 16];
      gbv[nt] = lnb[colb + nt * 16];
    }
#pragma unroll
    for (int i = 0; i < 4; i++) {
      int ra = 4 * g + i, rb = 16 + 4 * g + i;
      float t1a = red[ra] + red[64 + ra] + red[128 + ra] + red[192 + ra];
      float t2a = red[32 + ra] + red[96 + ra] + red[160 + ra] + red[224 + ra];
      float t1b = red[rb] + red[64 + rb] + red[128 + rb] + red[192 + rb];
      float t2b = red[32 + rb] + red[96 + rb] + red[160 + rb] + red[224 + rb];
      float mua = t1a * (1.f / 512.f);
      float inva = rsqrtf(t2a * (1.f / 512.f) - mua * mua + 1e-5f);
      float mub = t1b * (1.f / 512.f);
      float invb = rsqrtf(t2b * (1.f / 512.f) - mub * mub + 1e-5f);
      size_t offa = (size_t)(m0 + ra) * 512 + colb;
      size_t offb = (size_t)(m0 + rb) * 512 + colb;
#pragma unroll
      for (int nt = 0; nt < 8; nt++) {
        float ya = (acc0[nt][i] - mua) * inva * gw[nt] + gbv[nt];
        float yb2 = (acc1[nt][i] - mub) * invb * gw[nt] + gbv[nt];
        Yf[offa + nt * 16] = ya; Yb[offa + nt * 16] = f2bf(ya);
        Yf[offb + nt * 16] = yb2; Yb[offb + nt * 16] = f2bf(yb2);
      }
    }
  } else {
#pragma unroll
    for (int i = 0; i < 4; i++) {
      size_t offa = (size_t)(m0 + 4 * g + i) * 512 + colb;
      size_t offb = (size_t)(m0 + 16 + 4 * g + i) * 512 + colb;
#pragma unroll
      for (int nt = 0; nt < 8; nt++) {
        float va = acc0[nt][i], vb2 = acc1[nt][i];
        va = va / (1.f + __expf(-va));
        vb2 = vb2 / (1.f + __expf(-vb2));
        Yb[offa + nt * 16] = f2bf(va);
        Yb[offb + nt * 16] = f2bf(vb2);
      }
    }
  }
}

// ---------------- final projection: [8192,512] @ [32,512]^T + b ----------------
__global__ __launch_bounds__(256) void outp_kernel(
    const float* __restrict__ X, const float* __restrict__ W,
    const float* __restrict__ bias, float* __restrict__ Y)
{
  __shared__ __align__(16) float Xs[8][516];
  int t = threadIdx.x;
  int r = t >> 5, n = t & 31;
  size_t rowbase = (size_t)blockIdx.x * 8;
  const float* xp = X + (rowbase + r) * 512 + n * 16;
#pragma unroll
  for (int j = 0; j < 4; j++) {
    float4 v = *(const float4*)(xp + j * 4);
    *(float4*)&Xs[r][n * 16 + j * 4] = v;
  }
  __syncthreads();
  float acc = bias[n];
  const float* wp = W + (size_t)n * 512;
#pragma unroll 4
  for (int k0 = 0; k0 < 512; k0 += 4) {
    float4 h4 = *(const float4*)&Xs[r][k0];
    float4 w4 = *(const float4*)(wp + k0);
    acc += h4.x * w4.x + h4.y * w4.y + h4.z * w4.z + h4.w * w4.w;
  }
  Y[(rowbase + r) * 32 + n] = acc;
}

extern "C" void kernel_launch(void* const* d_in, const int* in_sizes, int n_in,
                              void* d_out, int out_size, void* d_ws, size_t ws_size,
                              hipStream_t stream) {
  (void)in_sizes; (void)n_in; (void)out_size; (void)ws_size;
  const float* x      = (const float*)d_in[0];
  const float* conv_w = (const float*)d_in[1];
  const float* conv_b = (const float*)d_in[2];
  const float* qkv_w  = (const float*)d_in[3];
  const float* qkv_b  = (const float*)d_in[4];
  const float* out_w  = (const float*)d_in[5];
  const float* out_b  = (const float*)d_in[6];
  const float* fc1_w  = (const float*)d_in[7];
  const float* fc1_b  = (const float*)d_in[8];
  const float* fc2_w  = (const float*)d_in[9];
  const float* fc2_b  = (const float*)d_in[10];
  const float* ln1_w  = (const float*)d_in[11];
  const float* ln1_b  = (const float*)d_in[12];
  const float* ln2_w  = (const float*)d_in[13];
  const float* ln2_b  = (const float*)d_in[14];
  const float* outp_w = (const float*)d_in[15];
  const float* outp_b = (const float*)d_in[16];
  float* out = (float*)d_out;

  char* p = (char*)d_ws;
  unsigned short* A_bf = (unsigned short*)p;            p += (size_t)8192 * 512 * 2;
  float*          A_f  = (float*)p;                     p += (size_t)8192 * 512 * 4;
  unsigned short* QKV  = (unsigned short*)p;            p += (size_t)8192 * 1536 * 2;
  unsigned short* VT   = (unsigned short*)p;            p += (size_t)32 * 64 * 2048 * 2;
  unsigned short* CTX  = (unsigned short*)p;            p += (size_t)8192 * 512 * 2;
  unsigned short* Wq   = (unsigned short*)p;            p += (size_t)4 * 1536 * 512 * 2;
  unsigned short* Wo   = (unsigned short*)p;            p += (size_t)4 * 512 * 512 * 2;
  unsigned short* W1   = (unsigned short*)p;            p += (size_t)4 * 512 * 512 * 2;
  unsigned short* W2   = (unsigned short*)p;            p += (size_t)4 * 512 * 512 * 2;

  f2bf_kernel<<<3072, 256, 0, stream>>>(qkv_w, Wq, 786432);
  f2bf_kernel<<<1024, 256, 0, stream>>>(out_w, Wo, 262144);
  f2bf_kernel<<<1024, 256, 0, stream>>>(fc1_w, W1, 262144);
  f2bf_kernel<<<1024, 256, 0, stream>>>(fc2_w, W2, 262144);

  conv_pe_kernel<<<1024, 256, 0, stream>>>(x, conv_w, conv_b, A_f, A_bf);

  for (int l = 0; l < 4; l++) {
    gemm_bf<0, 1><<<64 * 12, 256, 0, stream>>>(
        A_bf, Wq + (size_t)l * 1536 * 512, qkv_b + l * 1536, nullptr,
        QKV, nullptr, 1536);
    vtrans_kernel<<<1024, 256, 0, stream>>>(QKV, VT);
    attn_mfma<<<512, 256, 0, stream>>>(QKV, VT, CTX);
    gemm_ln<1><<<256, 256, 0, stream>>>(
        CTX, Wo + (size_t)l * 512 * 512, out_b + l * 512, A_f,
        ln1_w + l * 512, ln1_b + l * 512, A_f, A_bf);
    gemm_ln<0><<<256, 256, 0, stream>>>(
        A_bf, W1 + (size_t)l * 512 * 512, fc1_b + l * 512, nullptr,
        nullptr, nullptr, nullptr, CTX);
    gemm_ln<1><<<256, 256, 0, stream>>>(
        CTX, W2 + (size_t)l * 512 * 512, fc2_b + l * 512, A_f,
        ln2_w + l * 512, ln2_b + l * 512, A_f, A_bf);
  }
  outp_kernel<<<1024, 256, 0, stream>>>(A_f, outp_w, outp_b, out);
}

// Round 7
// 660.846 us; speedup vs baseline: 1.2118x; 1.2118x over previous
//
#include <hip/hip_runtime.h>
#include <hip/hip_bf16.h>
#include <cstddef>

typedef short bf16x8 __attribute__((ext_vector_type(8)));
typedef float f32x4 __attribute__((ext_vector_type(4)));

__device__ __forceinline__ unsigned short f2bf(float x) {
  __hip_bfloat16 h = __float2bfloat16(x);
  unsigned short u; __builtin_memcpy(&u, &h, 2); return u;
}
__device__ __forceinline__ float swz16f(float x) {   // lane ^= 16 (within 32-group)
  int i; __builtin_memcpy(&i, &x, 4);
  i = __builtin_amdgcn_ds_swizzle(i, 0x401F);
  float r; __builtin_memcpy(&r, &i, 4); return r;
}
__device__ __forceinline__ void gload16(const unsigned short* g, unsigned short* l) {
  __builtin_amdgcn_global_load_lds(
      (const __attribute__((address_space(1))) void*)g,
      (__attribute__((address_space(3))) void*)l, 16, 0, 0);
}
__device__ __forceinline__ void pipe_sync() {
  asm volatile("s_waitcnt vmcnt(0)" ::: "memory");
  __builtin_amdgcn_s_barrier();
  __builtin_amdgcn_sched_barrier(0);
}

// ---------------- weight fp32 -> bf16 convert ----------------
__global__ __launch_bounds__(256) void f2bf_kernel(
    const float* __restrict__ src, unsigned short* __restrict__ dst, int n4)
{
  int i = blockIdx.x * 256 + threadIdx.x;
  if (i < n4) {
    float4 v = *(const float4*)(src + (size_t)i * 4);
    ushort4 o;
    o.x = f2bf(v.x); o.y = f2bf(v.y); o.z = f2bf(v.z); o.w = f2bf(v.w);
    *(ushort4*)(dst + (size_t)i * 4) = o;
  }
}

// ---------------- conv1d (circular, k=3) + positional embedding ----------------
__global__ __launch_bounds__(256) void conv_pe_kernel(
    const float* __restrict__ x, const float* __restrict__ cw,
    const float* __restrict__ cb,
    float* __restrict__ outf, unsigned short* __restrict__ outb)
{
  const int L = 2048, CIN = 32;
  int b  = blockIdx.x >> 8;
  int l0 = (blockIdx.x & 255) << 3;
  int t  = threadIdx.x;
  __shared__ float xs[10][32];
  for (int idx = t; idx < 320; idx += 256) {
    int rr = idx >> 5, ci = idx & 31;
    int gl = (l0 - 1 + rr + L) & (L - 1);
    xs[rr][ci] = x[((size_t)b * L + gl) * CIN + ci];
  }
  __syncthreads();
  int e0 = t << 1;
  float acc0[8], acc1[8];
  float bb0 = cb[e0], bb1 = cb[e0 + 1];
#pragma unroll
  for (int li = 0; li < 8; li++) { acc0[li] = bb0; acc1[li] = bb1; }
  const float* w0p = cw + (size_t)e0 * 96;
  const float* w1p = w0p + 96;
  for (int ci = 0; ci < 32; ci++) {
#pragma unroll
    for (int kk = 0; kk < 3; kk++) {
      float w0 = w0p[ci * 3 + kk];
      float w1 = w1p[ci * 3 + kk];
#pragma unroll
      for (int li = 0; li < 8; li++) {
        float xv = xs[li + kk][ci];
        acc0[li] += xv * w0;
        acc1[li] += xv * w1;
      }
    }
  }
  float dv = __expf((float)e0 * (-9.210340371976184f / 512.0f));
#pragma unroll
  for (int li = 0; li < 8; li++) {
    int l = l0 + li;
    float arg = (float)l * dv;
    float sv = sinf(arg), cv = cosf(arg);
    float2 o; o.x = acc0[li] + sv; o.y = acc1[li] + cv;
    size_t off = ((size_t)b * L + l) * 512 + e0;
    *(float2*)&outf[off] = o;
    ushort2 ob; ob.x = f2bf(o.x); ob.y = f2bf(o.y);
    *(ushort2*)&outb[off] = ob;
  }
}

// ---------------- bf16 MFMA GEMM, 2-phase pipelined (T3-minimum) ----------------
// Y[M,N] = X[M,512] @ W[N,512]^T + bias.
// EPI 0: Yb bf16 (QSCALE: cols<512 prescaled).  EPI 1: Yf f32 = +R.  EPI 2: SiLU->Yb.
template<int EPI, int QSCALE>
__global__ __launch_bounds__(256) void gemm_bf(
    const unsigned short* __restrict__ X,
    const unsigned short* __restrict__ W,
    const float* __restrict__ bias,
    const float* __restrict__ R,
    unsigned short* __restrict__ Yb,
    float* __restrict__ Yf,
    int N)
{
  const int K = 512;
  __shared__ __align__(16) char smem[65536];   // [buf][Xs 16K | Ws 16K]
  int t = threadIdx.x;
  int lane = t & 63, wv = t >> 6;
  int g = lane >> 4, li = lane & 15;
  int m0 = (blockIdx.x & 63) << 7;
  int n0 = (blockIdx.x >> 6) << 7;
  int wm = (wv >> 1) << 6, wn = (wv & 1) << 6;

  int subrow = lane >> 3;
  int coloff = ((lane & 7) ^ subrow) << 3;   // inverse swizzle on global source

  f32x4 acc[4][4];
#pragma unroll
  for (int a = 0; a < 4; a++)
#pragma unroll
    for (int b2 = 0; b2 < 4; b2++) acc[a][b2] = (f32x4){0.f, 0.f, 0.f, 0.f};

  // prologue: stage k-step 0 into buf 0
#pragma unroll
  for (int j = 0; j < 4; j++) {
    int row = (wv * 4 + j) * 8 + subrow;
    gload16(X + (size_t)(m0 + row) * K + coloff,
            (unsigned short*)(smem + (wv * 4 + j) * 1024));
    gload16(W + (size_t)(n0 + row) * K + coloff,
            (unsigned short*)(smem + 16384 + (wv * 4 + j) * 1024));
  }
  pipe_sync();

#pragma unroll
  for (int ks = 0; ks < 8; ks++) {
    const int buf = ks & 1;
    char* cur = smem + buf * 32768;
    if (ks < 7) {                     // issue next-tile loads first (latency hides)
      char* nxt = smem + (buf ^ 1) * 32768;
      int k0 = (ks + 1) * 64;
#pragma unroll
      for (int j = 0; j < 4; j++) {
        int row = (wv * 4 + j) * 8 + subrow;
        gload16(X + (size_t)(m0 + row) * K + k0 + coloff,
                (unsigned short*)(nxt + (wv * 4 + j) * 1024));
        gload16(W + (size_t)(n0 + row) * K + k0 + coloff,
                (unsigned short*)(nxt + 16384 + (wv * 4 + j) * 1024));
      }
    }
#pragma unroll
    for (int s = 0; s < 2; s++) {
      bf16x8 af[4], bfr[4];
#pragma unroll
      for (int mt = 0; mt < 4; mt++) {
        int row = wm + 16 * mt + li;
        af[mt] = *(const bf16x8*)(cur + (row * 8 + ((g + 4 * s) ^ (row & 7))) * 16);
      }
#pragma unroll
      for (int nt = 0; nt < 4; nt++) {
        int row = wn + 16 * nt + li;
        bfr[nt] = *(const bf16x8*)(cur + 16384 +
                                   (row * 8 + ((g + 4 * s) ^ (row & 7))) * 16);
      }
#pragma unroll
      for (int mt = 0; mt < 4; mt++)
#pragma unroll
        for (int nt = 0; nt < 4; nt++)
          acc[mt][nt] = __builtin_amdgcn_mfma_f32_16x16x32_bf16(
              af[mt], bfr[nt], acc[mt][nt], 0, 0, 0);
    }
    pipe_sync();
  }

  float bv[4];
#pragma unroll
  for (int nt = 0; nt < 4; nt++) bv[nt] = bias[n0 + wn + 16 * nt + li];
#pragma unroll
  for (int mt = 0; mt < 4; mt++) {
#pragma unroll
    for (int i = 0; i < 4; i++) {
      size_t roff = (size_t)(m0 + wm + 16 * mt + 4 * g + i) * N;
#pragma unroll
      for (int nt = 0; nt < 4; nt++) {
        int col = n0 + wn + 16 * nt + li;
        float v = acc[mt][nt][i] + bv[nt];
        if (EPI == 1) {
          v += R[roff + col];
          Yf[roff + col] = v;
        } else if (EPI == 2) {
          v = v / (1.f + __expf(-v));
          Yb[roff + col] = f2bf(v);
        } else {
          if (QSCALE && col < 512) v *= 0.18033688011112042f;  // 0.125*log2(e)
          Yb[roff + col] = f2bf(v);
        }
      }
    }
  }
}

// ---------------- V transpose: qkv_bf V-part -> Vt[32][64][2048] ----------------
__global__ __launch_bounds__(256) void vtrans_kernel(
    const unsigned short* __restrict__ qkv, unsigned short* __restrict__ Vt)
{
  int ki = blockIdx.x & 31, bh = blockIdx.x >> 5;
  int b = bh >> 3, h = bh & 7;
  int kt = ki << 6;
  __shared__ unsigned short T[64][72];
  int t = threadIdx.x;
  int r = t >> 2, c0 = (t & 3) << 4;
  const unsigned short* src =
      qkv + ((size_t)(b * 2048 + kt + r)) * 1536 + 1024 + h * 64 + c0;
  bf16x8 a0 = *(const bf16x8*)src;
  bf16x8 a1 = *(const bf16x8*)(src + 8);
  *(bf16x8*)&T[r][c0] = a0;
  *(bf16x8*)&T[r][c0 + 8] = a1;
  __syncthreads();
  int d = t >> 2, k0 = (t & 3) << 4;
  bf16x8 v0, v1;
#pragma unroll
  for (int j = 0; j < 8; j++) v0[j] = (short)T[k0 + j][d];
#pragma unroll
  for (int j = 0; j < 8; j++) v1[j] = (short)T[k0 + 8 + j][d];
  unsigned short* dst = Vt + ((size_t)bh * 64 + d) * 2048 + kt + k0;
  *(bf16x8*)dst = v0;
  *(bf16x8*)(dst + 8) = v1;
}

// ---------------- MFMA flash attention, 2-phase pipelined ----------------
// QBLK=128; grid 16 x 32 bh; 256 thr = 4 waves; 64-key tiles; Q prescaled.
__global__ __launch_bounds__(256) void attn_mfma(
    const unsigned short* __restrict__ qkv,  // [8192,1536] bf16
    const unsigned short* __restrict__ Vt,   // [32,64,2048] bf16
    unsigned short* __restrict__ ctx)        // [8192,512] bf16
{
  const int L = 2048;
  int qi = blockIdx.x & 15, bh = blockIdx.x >> 4;
  int b = bh >> 3, h = bh & 7;
  int q0 = qi << 7;
  size_t tb = (size_t)b * L;
  int t = threadIdx.x, lane = t & 63, wv = t >> 6;
  int g = lane >> 4, li = lane & 15;
  int lisw = li & 7;

  // smem: buf0 [K 8K | V 8K] | buf1 [K 8K | V 8K] | P 16K  = 48K
  __shared__ __align__(16) char smem[49152];

  int wq = q0 + wv * 32;
  bf16x8 qf00, qf01, qf10, qf11;
  {
    const unsigned short* qp0 = qkv + (tb + wq + li) * 1536 + h * 64 + g * 8;
    qf00 = *(const bf16x8*)qp0;
    qf01 = *(const bf16x8*)(qp0 + 32);
    const unsigned short* qp1 = qp0 + (size_t)16 * 1536;
    qf10 = *(const bf16x8*)qp1;
    qf11 = *(const bf16x8*)(qp1 + 32);
  }

  f32x4 accA[4], accB[4];
#pragma unroll
  for (int nt = 0; nt < 4; nt++) {
    accA[nt] = (f32x4){0.f, 0.f, 0.f, 0.f};
    accB[nt] = (f32x4){0.f, 0.f, 0.f, 0.f};
  }
  float mA = -1e30f, mB = -1e30f, lA = 0.f, lB = 0.f;

  // fragment-read offsets (within a K/V buffer)
  int koff0 = li * 128 + ((g    ) ^ lisw) * 16;
  int koff1 = li * 128 + ((g + 4) ^ lisw) * 16;
  // P pointers (region at 32768, wave-private 4KB)
  const char* pb0 = smem + 32768 + wv * 4096 + koff0;
  const char* pb1 = smem + 32768 + wv * 4096 + koff1;
  char* pwbase = smem + 32768 + wv * 4096 + li * 128 + ((g & 1) << 3);
  char* pw0 = pwbase + (((0 + (g >> 1)) ^ lisw) << 4);
  char* pw1 = pwbase + (((2 + (g >> 1)) ^ lisw) << 4);
  char* pw2 = pwbase + (((4 + (g >> 1)) ^ lisw) << 4);
  char* pw3 = pwbase + (((6 + (g >> 1)) ^ lisw) << 4);

  // staging pointers
  int subrow = lane >> 3;
  int coloff = ((lane & 7) ^ subrow) << 3;
  int r0 = wv * 16 + subrow, r1 = wv * 16 + 8 + subrow;
  const unsigned short* kp0 = qkv + (tb + r0) * 1536 + 512 + h * 64 + coloff;
  const unsigned short* kp1 = qkv + (tb + r1) * 1536 + 512 + h * 64 + coloff;
  const unsigned short* vp0 = Vt + ((size_t)bh * 64 + r0) * 2048 + coloff;
  const unsigned short* vp1 = Vt + ((size_t)bh * 64 + r1) * 2048 + coloff;
  int dk0 = wv * 2048, dk1 = dk0 + 1024;           // byte offsets within K half
  int dv0 = 8192 + wv * 2048, dv1 = dv0 + 1024;    // within V half

  // prologue: stage tile 0 into buf 0
  gload16(kp0, (unsigned short*)(smem + dk0));
  gload16(kp1, (unsigned short*)(smem + dk1));
  gload16(vp0, (unsigned short*)(smem + dv0));
  gload16(vp1, (unsigned short*)(smem + dv1));
  kp0 += (size_t)64 * 1536; kp1 += (size_t)64 * 1536;
  vp0 += 64; vp1 += 64;
  pipe_sync();

#pragma unroll 2
  for (int it = 0; it < 32; it++) {
    const int buf = it & 1;
    const char* base = smem + buf * 16384;
    if (it < 31) {                    // issue next tile first (latency hides)
      char* nb = smem + (buf ^ 1) * 16384;
      gload16(kp0, (unsigned short*)(nb + dk0));
      gload16(kp1, (unsigned short*)(nb + dk1));
      gload16(vp0, (unsigned short*)(nb + dv0));
      gload16(vp1, (unsigned short*)(nb + dv1));
      kp0 += (size_t)64 * 1536; kp1 += (size_t)64 * 1536;
      vp0 += 64; vp1 += 64;
    }

    // S^T = K . Q^T  (kf shared across both q-frags)
    f32x4 sA[4], sB[4];
#pragma unroll
    for (int mt = 0; mt < 4; mt++) {
      sA[mt] = (f32x4){0.f, 0.f, 0.f, 0.f};
      sB[mt] = (f32x4){0.f, 0.f, 0.f, 0.f};
    }
#pragma unroll
    for (int mt = 0; mt < 4; mt++) {
      bf16x8 kf = *(const bf16x8*)(base + koff0 + mt * 2048);
      sA[mt] = __builtin_amdgcn_mfma_f32_16x16x32_bf16(kf, qf00, sA[mt], 0, 0, 0);
      sB[mt] = __builtin_amdgcn_mfma_f32_16x16x32_bf16(kf, qf10, sB[mt], 0, 0, 0);
    }
#pragma unroll
    for (int mt = 0; mt < 4; mt++) {
      bf16x8 kf = *(const bf16x8*)(base + koff1 + mt * 2048);
      sA[mt] = __builtin_amdgcn_mfma_f32_16x16x32_bf16(kf, qf01, sA[mt], 0, 0, 0);
      sB[mt] = __builtin_amdgcn_mfma_f32_16x16x32_bf16(kf, qf11, sB[mt], 0, 0, 0);
    }

    // tile maxes
    float mxA, mxB;
    {
      float a0 = fmaxf(fmaxf(sA[0][0], sA[0][1]), fmaxf(sA[0][2], sA[0][3]));
      float a1 = fmaxf(fmaxf(sA[1][0], sA[1][1]), fmaxf(sA[1][2], sA[1][3]));
      float a2 = fmaxf(fmaxf(sA[2][0], sA[2][1]), fmaxf(sA[2][2], sA[2][3]));
      float a3 = fmaxf(fmaxf(sA[3][0], sA[3][1]), fmaxf(sA[3][2], sA[3][3]));
      mxA = fmaxf(fmaxf(a0, a1), fmaxf(a2, a3));
      float b0 = fmaxf(fmaxf(sB[0][0], sB[0][1]), fmaxf(sB[0][2], sB[0][3]));
      float b1 = fmaxf(fmaxf(sB[1][0], sB[1][1]), fmaxf(sB[1][2], sB[1][3]));
      float b2 = fmaxf(fmaxf(sB[2][0], sB[2][1]), fmaxf(sB[2][2], sB[2][3]));
      float b3 = fmaxf(fmaxf(sB[3][0], sB[3][1]), fmaxf(sB[3][2], sB[3][3]));
      mxB = fmaxf(fmaxf(b0, b1), fmaxf(b2, b3));
    }
    mxA = fmaxf(mxA, swz16f(mxA)); mxA = fmaxf(mxA, __shfl_xor(mxA, 32));
    mxB = fmaxf(mxB, swz16f(mxB)); mxB = fmaxf(mxB, __shfl_xor(mxB, 32));

    // defer-max (THR=8, exp2 domain)
    if (__any((mxA > mA + 8.0f) || (mxB > mB + 8.0f))) {
      float mnA = fmaxf(mA, mxA), mnB = fmaxf(mB, mxB);
      float cA = mA - mnA, cB = mB - mnB;
      asm volatile("v_exp_f32 %0, %0\n\tv_exp_f32 %1, %1\n\ts_nop 1"
                   : "+v"(cA), "+v"(cB));
      float c0 = __shfl(cA, 4 * g + 0), c1 = __shfl(cA, 4 * g + 1);
      float c2 = __shfl(cA, 4 * g + 2), c3 = __shfl(cA, 4 * g + 3);
#pragma unroll
      for (int nt = 0; nt < 4; nt++) {
        accA[nt][0] *= c0; accA[nt][1] *= c1;
        accA[nt][2] *= c2; accA[nt][3] *= c3;
      }
      float d0 = __shfl(cB, 4 * g + 0), d1 = __shfl(cB, 4 * g + 1);
      float d2 = __shfl(cB, 4 * g + 2), d3 = __shfl(cB, 4 * g + 3);
#pragma unroll
      for (int nt = 0; nt < 4; nt++) {
        accB[nt][0] *= d0; accB[nt][1] *= d1;
        accB[nt][2] *= d2; accB[nt][3] *= d3;
      }
      lA *= cA; lB *= cB;
      mA = mnA; mB = mnB;
    }

    // p = 2^(s-m), sum, cvt_pk, LDS write (wave-private P rows)
    float psA = 0.f, psB = 0.f;
#define PBLK(SARR, MM, PS, PWP, OFF)                                          \
    {                                                                         \
      float p0 = SARR[0] - MM, p1 = SARR[1] - MM,                             \
            p2 = SARR[2] - MM, p3 = SARR[3] - MM;                             \
      asm volatile("v_exp_f32 %0, %0\n\tv_exp_f32 %1, %1\n\t"                 \
                   "v_exp_f32 %2, %2\n\tv_exp_f32 %3, %3\n\ts_nop 1"          \
                   : "+v"(p0), "+v"(p1), "+v"(p2), "+v"(p3));                 \
      PS += (p0 + p1) + (p2 + p3);                                            \
      uint2 pv;                                                               \
      asm("v_cvt_pk_bf16_f32 %0, %1, %2" : "=v"(pv.x) : "v"(p0), "v"(p1));    \
      asm("v_cvt_pk_bf16_f32 %0, %1, %2" : "=v"(pv.y) : "v"(p2), "v"(p3));    \
      *(uint2*)(PWP + OFF) = pv;                                              \
    }
    PBLK(sA[0], mA, psA, pw0, 0) PBLK(sA[1], mA, psA, pw1, 0)
    PBLK(sA[2], mA, psA, pw2, 0) PBLK(sA[3], mA, psA, pw3, 0)
    PBLK(sB[0], mB, psB, pw0, 2048) PBLK(sB[1], mB, psB, pw1, 2048)
    PBLK(sB[2], mB, psB, pw2, 2048) PBLK(sB[3], mB, psB, pw3, 2048)
#undef PBLK
    psA += swz16f(psA); psA += __shfl_xor(psA, 32); lA += psA;
    psB += swz16f(psB); psB += __shfl_xor(psB, 32); lB += psB;

    // O += P . V  (vb shared across both frags)
    {
      bf16x8 paA0 = *(const bf16x8*)(pb0);
      bf16x8 paB0 = *(const bf16x8*)(pb0 + 2048);
#pragma unroll
      for (int nt = 0; nt < 4; nt++) {
        bf16x8 vb = *(const bf16x8*)(base + 8192 + koff0 + nt * 2048);
        accA[nt] = __builtin_amdgcn_mfma_f32_16x16x32_bf16(paA0, vb, accA[nt], 0, 0, 0);
        accB[nt] = __builtin_amdgcn_mfma_f32_16x16x32_bf16(paB0, vb, accB[nt], 0, 0, 0);
      }
      bf16x8 paA1 = *(const bf16x8*)(pb1);
      bf16x8 paB1 = *(const bf16x8*)(pb1 + 2048);
#pragma unroll
      for (int nt = 0; nt < 4; nt++) {
        bf16x8 vb = *(const bf16x8*)(base + 8192 + koff1 + nt * 2048);
        accA[nt] = __builtin_amdgcn_mfma_f32_16x16x32_bf16(paA1, vb, accA[nt], 0, 0, 0);
        accB[nt] = __builtin_amdgcn_mfma_f32_16x16x32_bf16(paB1, vb, accB[nt], 0, 0, 0);
      }
    }
    pipe_sync();
  }

  float liA[4], liB[4];
#pragma unroll
  for (int i = 0; i < 4; i++) {
    liA[i] = 1.f / __shfl(lA, 4 * g + i);
    liB[i] = 1.f / __shfl(lB, 4 * g + i);
  }
#pragma unroll
  for (int i = 0; i < 4; i++) {
    size_t ra = (tb + wq + 4 * g + i) * 512 + h * 64;
    size_t rb = (tb + wq + 16 + 4 * g + i) * 512 + h * 64;
#pragma unroll
    for (int nt = 0; nt < 4; nt++) {
      ctx[ra + 16 * nt + li] = f2bf(accA[nt][i] * liA[i]);
      ctx[rb + 16 * nt + li] = f2bf(accB[nt][i] * liB[i]);
    }
  }
}

// ---------------- LayerNorm over E=512; one wave per row; f32 + bf16 out ------
__global__ __launch_bounds__(256) void ln_kernel(
    const float* __restrict__ X, const float* __restrict__ g,
    const float* __restrict__ b, float* __restrict__ Yf,
    unsigned short* __restrict__ Yb)
{
  int t = threadIdx.x, lane = t & 63, wv = t >> 6;
  size_t row = (size_t)blockIdx.x * 4 + wv;
  const float* xp = X + row * 512 + lane * 8;
  float4 a = *(const float4*)xp;
  float4 c = *(const float4*)(xp + 4);
  float sum = a.x + a.y + a.z + a.w + c.x + c.y + c.z + c.w;
  float sq  = a.x*a.x + a.y*a.y + a.z*a.z + a.w*a.w
            + c.x*c.x + c.y*c.y + c.z*c.z + c.w*c.w;
#pragma unroll
  for (int off = 32; off > 0; off >>= 1) {
    sum += __shfl_xor(sum, off);
    sq  += __shfl_xor(sq, off);
  }
  float mu  = sum * (1.0f / 512.0f);
  float inv = rsqrtf(sq * (1.0f / 512.0f) - mu * mu + 1e-5f);
  float4 g0 = *(const float4*)(g + lane * 8);
  float4 g1 = *(const float4*)(g + lane * 8 + 4);
  float4 b0 = *(const float4*)(b + lane * 8);
  float4 b1 = *(const float4*)(b + lane * 8 + 4);
  float y[8];
  y[0] = (a.x - mu) * inv * g0.x + b0.x;
  y[1] = (a.y - mu) * inv * g0.y + b0.y;
  y[2] = (a.z - mu) * inv * g0.z + b0.z;
  y[3] = (a.w - mu) * inv * g0.w + b0.w;
  y[4] = (c.x - mu) * inv * g1.x + b1.x;
  y[5] = (c.y - mu) * inv * g1.y + b1.y;
  y[6] = (c.z - mu) * inv * g1.z + b1.z;
  y[7] = (c.w - mu) * inv * g1.w + b1.w;
  float4 y0 = {y[0], y[1], y[2], y[3]};
  float4 y1 = {y[4], y[5], y[6], y[7]};
  *(float4*)(Yf + row * 512 + lane * 8)     = y0;
  *(float4*)(Yf + row * 512 + lane * 8 + 4) = y1;
  bf16x8 yb;
#pragma unroll
  for (int j = 0; j < 8; j++) yb[j] = (short)f2bf(y[j]);
  *(bf16x8*)(Yb + row * 512 + lane * 8) = yb;
}

// ---------------- final projection: [8192,512] @ [32,512]^T + b ----------------
__global__ __launch_bounds__(256) void outp_kernel(
    const float* __restrict__ X, const float* __restrict__ W,
    const float* __restrict__ bias, float* __restrict__ Y)
{
  __shared__ __align__(16) float Xs[8][516];
  int t = threadIdx.x;
  int r = t >> 5, n = t & 31;
  size_t rowbase = (size_t)blockIdx.x * 8;
  const float* xp = X + (rowbase + r) * 512 + n * 16;
#pragma unroll
  for (int j = 0; j < 4; j++) {
    float4 v = *(const float4*)(xp + j * 4);
    *(float4*)&Xs[r][n * 16 + j * 4] = v;
  }
  __syncthreads();
  float acc = bias[n];
  const float* wp = W + (size_t)n * 512;
#pragma unroll 4
  for (int k0 = 0; k0 < 512; k0 += 4) {
    float4 h4 = *(const float4*)&Xs[r][k0];
    float4 w4 = *(const float4*)(wp + k0);
    acc += h4.x * w4.x + h4.y * w4.y + h4.z * w4.z + h4.w * w4.w;
  }
  Y[(rowbase + r) * 32 + n] = acc;
}

extern "C" void kernel_launch(void* const* d_in, const int* in_sizes, int n_in,
                              void* d_out, int out_size, void* d_ws, size_t ws_size,
                              hipStream_t stream) {
  (void)in_sizes; (void)n_in; (void)out_size; (void)ws_size;
  const float* x      = (const float*)d_in[0];
  const float* conv_w = (const float*)d_in[1];
  const float* conv_b = (const float*)d_in[2];
  const float* qkv_w  = (const float*)d_in[3];
  const float* qkv_b  = (const float*)d_in[4];
  const float* out_w  = (const float*)d_in[5];
  const float* out_b  = (const float*)d_in[6];
  const float* fc1_w  = (const float*)d_in[7];
  const float* fc1_b  = (const float*)d_in[8];
  const float* fc2_w  = (const float*)d_in[9];
  const float* fc2_b  = (const float*)d_in[10];
  const float* ln1_w  = (const float*)d_in[11];
  const float* ln1_b  = (const float*)d_in[12];
  const float* ln2_w  = (const float*)d_in[13];
  const float* ln2_b  = (const float*)d_in[14];
  const float* outp_w = (const float*)d_in[15];
  const float* outp_b = (const float*)d_in[16];
  float* out = (float*)d_out;

  char* p = (char*)d_ws;
  unsigned short* A_bf = (unsigned short*)p;            p += (size_t)8192 * 512 * 2;
  float*          A_f  = (float*)p;                     p += (size_t)8192 * 512 * 4;
  unsigned short* QKV  = (unsigned short*)p;            p += (size_t)8192 * 1536 * 2;
  unsigned short* VT   = (unsigned short*)p;            p += (size_t)32 * 64 * 2048 * 2;
  unsigned short* CTX  = (unsigned short*)p;            p += (size_t)8192 * 512 * 2;
  unsigned short* Wq   = (unsigned short*)p;            p += (size_t)4 * 1536 * 512 * 2;
  unsigned short* Wo   = (unsigned short*)p;            p += (size_t)4 * 512 * 512 * 2;
  unsigned short* W1   = (unsigned short*)p;            p += (size_t)4 * 512 * 512 * 2;
  unsigned short* W2   = (unsigned short*)p;            p += (size_t)4 * 512 * 512 * 2;
  float* D = (float*)QKV;   // aliased: D[8192,512] f32 in QKV region (disjoint lifetime)

  f2bf_kernel<<<3072, 256, 0, stream>>>(qkv_w, Wq, 786432);
  f2bf_kernel<<<1024, 256, 0, stream>>>(out_w, Wo, 262144);
  f2bf_kernel<<<1024, 256, 0, stream>>>(fc1_w, W1, 262144);
  f2bf_kernel<<<1024, 256, 0, stream>>>(fc2_w, W2, 262144);

  conv_pe_kernel<<<1024, 256, 0, stream>>>(x, conv_w, conv_b, A_f, A_bf);

  for (int l = 0; l < 4; l++) {
    gemm_bf<0, 1><<<64 * 12, 256, 0, stream>>>(
        A_bf, Wq + (size_t)l * 1536 * 512, qkv_b + l * 1536, nullptr,
        QKV, nullptr, 1536);
    vtrans_kernel<<<1024, 256, 0, stream>>>(QKV, VT);
    attn_mfma<<<512, 256, 0, stream>>>(QKV, VT, CTX);
    gemm_bf<1, 0><<<64 * 4, 256, 0, stream>>>(
        CTX, Wo + (size_t)l * 512 * 512, out_b + l * 512, A_f,
        nullptr, D, 512);
    ln_kernel<<<2048, 256, 0, stream>>>(D, ln1_w + l * 512, ln1_b + l * 512, A_f, A_bf);
    gemm_bf<2, 0><<<64 * 4, 256, 0, stream>>>(
        A_bf, W1 + (size_t)l * 512 * 512, fc1_b + l * 512, nullptr,
        CTX, nullptr, 512);
    gemm_bf<1, 0><<<64 * 4, 256, 0, stream>>>(
        CTX, W2 + (size_t)l * 512 * 512, fc2_b + l * 512, A_f,
        nullptr, D, 512);
    ln_kernel<<<2048, 256, 0, stream>>>(D, ln2_w + l * 512, ln2_b + l * 512, A_f, A_bf);
  }
  outp_kernel<<<1024, 256, 0, stream>>>(A_f, outp_w, outp_b, out);
}

// Round 8
// 628.960 us; speedup vs baseline: 1.2732x; 1.0507x over previous
//
#include <hip/hip_runtime.h>
#include <hip/hip_bf16.h>
#include <cstddef>

typedef short bf16x8 __attribute__((ext_vector_type(8)));
typedef float f32x4 __attribute__((ext_vector_type(4)));

__device__ __forceinline__ unsigned short f2bf(float x) {
  __hip_bfloat16 h = __float2bfloat16(x);
  unsigned short u; __builtin_memcpy(&u, &h, 2); return u;
}
__device__ __forceinline__ float swz16f(float x) {   // lane ^= 16 (within 32-group)
  int i; __builtin_memcpy(&i, &x, 4);
  i = __builtin_amdgcn_ds_swizzle(i, 0x401F);
  float r; __builtin_memcpy(&r, &i, 4); return r;
}
__device__ __forceinline__ void gload16(const unsigned short* g, unsigned short* l) {
  __builtin_amdgcn_global_load_lds(
      (const __attribute__((address_space(1))) void*)g,
      (__attribute__((address_space(3))) void*)l, 16, 0, 0);
}
__device__ __forceinline__ void pipe_sync() {
  asm volatile("s_waitcnt vmcnt(0)" ::: "memory");
  __builtin_amdgcn_s_barrier();
  __builtin_amdgcn_sched_barrier(0);
}

// ---------------- weight fp32 -> bf16 convert ----------------
__global__ __launch_bounds__(256) void f2bf_kernel(
    const float* __restrict__ src, unsigned short* __restrict__ dst, int n4)
{
  int i = blockIdx.x * 256 + threadIdx.x;
  if (i < n4) {
    float4 v = *(const float4*)(src + (size_t)i * 4);
    ushort4 o;
    o.x = f2bf(v.x); o.y = f2bf(v.y); o.z = f2bf(v.z); o.w = f2bf(v.w);
    *(ushort4*)(dst + (size_t)i * 4) = o;
  }
}

// ---------------- conv1d (circular, k=3) + positional embedding ----------------
__global__ __launch_bounds__(256) void conv_pe_kernel(
    const float* __restrict__ x, const float* __restrict__ cw,
    const float* __restrict__ cb,
    float* __restrict__ outf, unsigned short* __restrict__ outb)
{
  const int L = 2048, CIN = 32;
  int b  = blockIdx.x >> 8;
  int l0 = (blockIdx.x & 255) << 3;
  int t  = threadIdx.x;
  __shared__ float xs[10][32];
  for (int idx = t; idx < 320; idx += 256) {
    int rr = idx >> 5, ci = idx & 31;
    int gl = (l0 - 1 + rr + L) & (L - 1);
    xs[rr][ci] = x[((size_t)b * L + gl) * CIN + ci];
  }
  __syncthreads();
  int e0 = t << 1;
  float acc0[8], acc1[8];
  float bb0 = cb[e0], bb1 = cb[e0 + 1];
#pragma unroll
  for (int li = 0; li < 8; li++) { acc0[li] = bb0; acc1[li] = bb1; }
  const float* w0p = cw + (size_t)e0 * 96;
  const float* w1p = w0p + 96;
  for (int ci = 0; ci < 32; ci++) {
#pragma unroll
    for (int kk = 0; kk < 3; kk++) {
      float w0 = w0p[ci * 3 + kk];
      float w1 = w1p[ci * 3 + kk];
#pragma unroll
      for (int li = 0; li < 8; li++) {
        float xv = xs[li + kk][ci];
        acc0[li] += xv * w0;
        acc1[li] += xv * w1;
      }
    }
  }
  float dv = __expf((float)e0 * (-9.210340371976184f / 512.0f));
#pragma unroll
  for (int li = 0; li < 8; li++) {
    int l = l0 + li;
    float arg = (float)l * dv;
    float sv = sinf(arg), cv = cosf(arg);
    float2 o; o.x = acc0[li] + sv; o.y = acc1[li] + cv;
    size_t off = ((size_t)b * L + l) * 512 + e0;
    *(float2*)&outf[off] = o;
    ushort2 ob; ob.x = f2bf(o.x); ob.y = f2bf(o.y);
    *(ushort2*)&outb[off] = ob;
  }
}

// ---------------- bf16 MFMA GEMM, 2-phase pipelined ----------------
// Y[M,N] = X[M,512] @ W[N,512]^T + bias.  Tile 128 x (NFR*32).
// EPI 0: Yb bf16 (QSCALE: cols<512 prescaled).  EPI 1: Yf f32 = +R.  EPI 2: SiLU->Yb.
template<int EPI, int QSCALE, int NFR>
__global__ __launch_bounds__(256) void gemm_bf(
    const unsigned short* __restrict__ X,
    const unsigned short* __restrict__ W,
    const float* __restrict__ bias,
    const float* __restrict__ R,
    unsigned short* __restrict__ Yb,
    float* __restrict__ Yf,
    int N)
{
  const int K = 512;
  constexpr int BN = NFR * 32;
  constexpr int WB = NFR * 4096;          // W-region bytes per buffer
  constexpr int BUF = 16384 + WB;
  __shared__ __align__(16) char smem[2 * BUF];
  int t = threadIdx.x;
  int lane = t & 63, wv = t >> 6;
  int g = lane >> 4, li = lane & 15;
  int m0 = (blockIdx.x & 63) << 7;
  int n0 = (blockIdx.x >> 6) * BN;
  int wm = (wv >> 1) << 6;
  int wn = (wv & 1) * (BN / 2);

  int subrow = lane >> 3;
  int coloff = ((lane & 7) ^ subrow) << 3;   // inverse swizzle on global source

  f32x4 acc[4][NFR];
#pragma unroll
  for (int a = 0; a < 4; a++)
#pragma unroll
    for (int b2 = 0; b2 < NFR; b2++) acc[a][b2] = (f32x4){0.f, 0.f, 0.f, 0.f};

  // prologue: stage k-step 0 into buf 0
#pragma unroll
  for (int j = 0; j < 4; j++) {
    int row = (wv * 4 + j) * 8 + subrow;
    gload16(X + (size_t)(m0 + row) * K + coloff,
            (unsigned short*)(smem + (wv * 4 + j) * 1024));
  }
#pragma unroll
  for (int j = 0; j < NFR; j++) {
    int row = (wv * NFR + j) * 8 + subrow;
    gload16(W + (size_t)(n0 + row) * K + coloff,
            (unsigned short*)(smem + 16384 + (wv * NFR + j) * 1024));
  }
  pipe_sync();

#pragma unroll
  for (int ks = 0; ks < 8; ks++) {
    const int buf = ks & 1;
    char* cur = smem + buf * BUF;
    if (ks < 7) {                     // issue next-tile loads first
      char* nxt = smem + (buf ^ 1) * BUF;
      int k0 = (ks + 1) * 64;
#pragma unroll
      for (int j = 0; j < 4; j++) {
        int row = (wv * 4 + j) * 8 + subrow;
        gload16(X + (size_t)(m0 + row) * K + k0 + coloff,
                (unsigned short*)(nxt + (wv * 4 + j) * 1024));
      }
#pragma unroll
      for (int j = 0; j < NFR; j++) {
        int row = (wv * NFR + j) * 8 + subrow;
        gload16(W + (size_t)(n0 + row) * K + k0 + coloff,
                (unsigned short*)(nxt + 16384 + (wv * NFR + j) * 1024));
      }
    }
#pragma unroll
    for (int s = 0; s < 2; s++) {
      bf16x8 af[4], bfr[NFR];
#pragma unroll
      for (int mt = 0; mt < 4; mt++) {
        int row = wm + 16 * mt + li;
        af[mt] = *(const bf16x8*)(cur + (row * 8 + ((g + 4 * s) ^ (row & 7))) * 16);
      }
#pragma unroll
      for (int nt = 0; nt < NFR; nt++) {
        int row = wn + 16 * nt + li;
        bfr[nt] = *(const bf16x8*)(cur + 16384 +
                                   (row * 8 + ((g + 4 * s) ^ (row & 7))) * 16);
      }
#pragma unroll
      for (int mt = 0; mt < 4; mt++)
#pragma unroll
        for (int nt = 0; nt < NFR; nt++)
          acc[mt][nt] = __builtin_amdgcn_mfma_f32_16x16x32_bf16(
              af[mt], bfr[nt], acc[mt][nt], 0, 0, 0);
    }
    pipe_sync();
  }

  float bv[NFR];
#pragma unroll
  for (int nt = 0; nt < NFR; nt++) bv[nt] = bias[n0 + wn + 16 * nt + li];
#pragma unroll
  for (int mt = 0; mt < 4; mt++) {
#pragma unroll
    for (int i = 0; i < 4; i++) {
      size_t roff = (size_t)(m0 + wm + 16 * mt + 4 * g + i) * N;
#pragma unroll
      for (int nt = 0; nt < NFR; nt++) {
        int col = n0 + wn + 16 * nt + li;
        float v = acc[mt][nt][i] + bv[nt];
        if (EPI == 1) {
          v += R[roff + col];
          Yf[roff + col] = v;
        } else if (EPI == 2) {
          v = v / (1.f + __expf(-v));
          Yb[roff + col] = f2bf(v);
        } else {
          if (QSCALE && col < 512) v *= 0.18033688011112042f;  // 0.125*log2(e)
          Yb[roff + col] = f2bf(v);
        }
      }
    }
  }
}

// ---------------- V transpose: qkv_bf V-part -> Vt[32][64][2048] ----------------
__global__ __launch_bounds__(256) void vtrans_kernel(
    const unsigned short* __restrict__ qkv, unsigned short* __restrict__ Vt)
{
  int ki = blockIdx.x & 31, bh = blockIdx.x >> 5;
  int b = bh >> 3, h = bh & 7;
  int kt = ki << 6;
  __shared__ unsigned short T[64][72];
  int t = threadIdx.x;
  int r = t >> 2, c0 = (t & 3) << 4;
  const unsigned short* src =
      qkv + ((size_t)(b * 2048 + kt + r)) * 1536 + 1024 + h * 64 + c0;
  bf16x8 a0 = *(const bf16x8*)src;
  bf16x8 a1 = *(const bf16x8*)(src + 8);
  *(bf16x8*)&T[r][c0] = a0;
  *(bf16x8*)&T[r][c0 + 8] = a1;
  __syncthreads();
  int d = t >> 2, k0 = (t & 3) << 4;
  bf16x8 v0, v1;
#pragma unroll
  for (int j = 0; j < 8; j++) v0[j] = (short)T[k0 + j][d];
#pragma unroll
  for (int j = 0; j < 8; j++) v1[j] = (short)T[k0 + 8 + j][d];
  unsigned short* dst = Vt + ((size_t)bh * 64 + d) * 2048 + kt + k0;
  *(bf16x8*)dst = v0;
  *(bf16x8*)(dst + 8) = v1;
}

// ---------------- MFMA flash attention, 2-phase pipelined, KVBLK=128 ----------
// QBLK=128; grid 16 x 32 bh; 256 thr = 4 waves; Q prescaled by 0.125*log2(e).
__global__ __launch_bounds__(256) void attn_mfma(
    const unsigned short* __restrict__ qkv,  // [8192,1536] bf16
    const unsigned short* __restrict__ Vt,   // [32,64,2048] bf16
    unsigned short* __restrict__ ctx)        // [8192,512] bf16
{
  const int L = 2048;
  int qi = blockIdx.x & 15, bh = blockIdx.x >> 4;
  int b = bh >> 3, h = bh & 7;
  int q0 = qi << 7;
  size_t tb = (size_t)b * L;
  int t = threadIdx.x, lane = t & 63, wv = t >> 6;
  int g = lane >> 4, li = lane & 15;
  int lisw = li & 7;

  // smem: buf{0,1}: [K 16K | V 16K] at 0/32768 ; P 16K at 65536 (4K/wave)
  __shared__ __align__(16) char smem[81920];

  int wq = q0 + wv * 32;
  bf16x8 qf00, qf01, qf10, qf11;
  {
    const unsigned short* qp0 = qkv + (tb + wq + li) * 1536 + h * 64 + g * 8;
    qf00 = *(const bf16x8*)qp0;
    qf01 = *(const bf16x8*)(qp0 + 32);
    const unsigned short* qp1 = qp0 + (size_t)16 * 1536;
    qf10 = *(const bf16x8*)qp1;
    qf11 = *(const bf16x8*)(qp1 + 32);
  }

  f32x4 accA[4], accB[4];
#pragma unroll
  for (int nt = 0; nt < 4; nt++) {
    accA[nt] = (f32x4){0.f, 0.f, 0.f, 0.f};
    accB[nt] = (f32x4){0.f, 0.f, 0.f, 0.f};
  }
  float mA = -1e30f, mB = -1e30f, lA = 0.f, lB = 0.f;

  // K fragment offsets (K region rows = 128B): row = 16mt+li
  int koff0 = li * 128 + ((g    ) ^ lisw) * 16;
  int koff1 = li * 128 + ((g + 4) ^ lisw) * 16;
  // V fragment offsets (V region rows = 256B, 16 slots): row = 16nt+li
  int vrowb = 16384 + li * 256;
  int vs00 = ((g    ) ^ lisw) << 4;     // pass 0, d-half 0
  int vs01 = ((g + 4) ^ lisw) << 4;     // pass 0, d-half 1
  int vs10 = ((8 + g) ^ lisw) << 4;     // pass 1, d-half 0
  int vs11 = ((12 + g) ^ lisw) << 4;    // pass 1, d-half 1
  // P pointers (wave-private 4KB at 65536)
  const char* pb0 = smem + 65536 + wv * 4096 + li * 128 + ((g    ) ^ lisw) * 16;
  const char* pb1 = smem + 65536 + wv * 4096 + li * 128 + ((g + 4) ^ lisw) * 16;
  char* pwbase = smem + 65536 + wv * 4096 + li * 128 + ((g & 1) << 3);
  char* pw0 = pwbase + (((0 + (g >> 1)) ^ lisw) << 4);
  char* pw1 = pwbase + (((2 + (g >> 1)) ^ lisw) << 4);
  char* pw2 = pwbase + (((4 + (g >> 1)) ^ lisw) << 4);
  char* pw3 = pwbase + (((6 + (g >> 1)) ^ lisw) << 4);

  // staging pointers: K 4 issues (rows 0..127), V 4 issues (rows 0..63)
  int subrow = lane >> 3;
  int coloff = ((lane & 7) ^ subrow) << 3;
  const unsigned short* kp[4];
  const unsigned short* vp[4];
#pragma unroll
  for (int j = 0; j < 4; j++) {
    int krow = (wv * 4 + j) * 8 + subrow;
    kp[j] = qkv + (tb + krow) * 1536 + 512 + h * 64 + coloff;
    int vrow = (wv * 4 + j) * 4 + g;
    vp[j] = Vt + ((size_t)bh * 64 + vrow) * 2048 + ((li ^ (vrow & 7)) << 3);
  }

  // prologue: stage tile 0 into buf 0
#pragma unroll
  for (int j = 0; j < 4; j++) {
    gload16(kp[j], (unsigned short*)(smem + (wv * 4 + j) * 1024));
    gload16(vp[j], (unsigned short*)(smem + 16384 + (wv * 4 + j) * 1024));
    kp[j] += (size_t)128 * 1536; vp[j] += 128;
  }
  pipe_sync();

#pragma unroll 2
  for (int it = 0; it < 16; it++) {
    const int buf = it & 1;
    const char* base = smem + buf * 32768;
    if (it < 15) {                    // issue next tile first (latency hides)
      char* nb = smem + (buf ^ 1) * 32768;
#pragma unroll
      for (int j = 0; j < 4; j++) {
        gload16(kp[j], (unsigned short*)(nb + (wv * 4 + j) * 1024));
        gload16(vp[j], (unsigned short*)(nb + 16384 + (wv * 4 + j) * 1024));
        kp[j] += (size_t)128 * 1536; vp[j] += 128;
      }
    }

    // S^T = K . Q^T over 128 keys (8 fragments per d-half)
    f32x4 sA[8], sB[8];
#pragma unroll
    for (int mt = 0; mt < 8; mt++) {
      sA[mt] = (f32x4){0.f, 0.f, 0.f, 0.f};
      sB[mt] = (f32x4){0.f, 0.f, 0.f, 0.f};
    }
#pragma unroll
    for (int mt = 0; mt < 8; mt++) {
      bf16x8 kf = *(const bf16x8*)(base + koff0 + mt * 2048);
      sA[mt] = __builtin_amdgcn_mfma_f32_16x16x32_bf16(kf, qf00, sA[mt], 0, 0, 0);
      sB[mt] = __builtin_amdgcn_mfma_f32_16x16x32_bf16(kf, qf10, sB[mt], 0, 0, 0);
    }
#pragma unroll
    for (int mt = 0; mt < 8; mt++) {
      bf16x8 kf = *(const bf16x8*)(base + koff1 + mt * 2048);
      sA[mt] = __builtin_amdgcn_mfma_f32_16x16x32_bf16(kf, qf01, sA[mt], 0, 0, 0);
      sB[mt] = __builtin_amdgcn_mfma_f32_16x16x32_bf16(kf, qf11, sB[mt], 0, 0, 0);
    }

    // tile maxes over 128 keys
    float mxA = -1e30f, mxB = -1e30f;
#pragma unroll
    for (int mt = 0; mt < 8; mt++) {
      mxA = fmaxf(mxA, fmaxf(fmaxf(sA[mt][0], sA[mt][1]), fmaxf(sA[mt][2], sA[mt][3])));
      mxB = fmaxf(mxB, fmaxf(fmaxf(sB[mt][0], sB[mt][1]), fmaxf(sB[mt][2], sB[mt][3])));
    }
    mxA = fmaxf(mxA, swz16f(mxA)); mxA = fmaxf(mxA, __shfl_xor(mxA, 32));
    mxB = fmaxf(mxB, swz16f(mxB)); mxB = fmaxf(mxB, __shfl_xor(mxB, 32));

    // defer-max (THR=8, exp2 domain)
    if (__any((mxA > mA + 8.0f) || (mxB > mB + 8.0f))) {
      float mnA = fmaxf(mA, mxA), mnB = fmaxf(mB, mxB);
      float cA = mA - mnA, cB = mB - mnB;
      asm volatile("v_exp_f32 %0, %0\n\tv_exp_f32 %1, %1\n\ts_nop 1"
                   : "+v"(cA), "+v"(cB));
      float c0 = __shfl(cA, 4 * g + 0), c1 = __shfl(cA, 4 * g + 1);
      float c2 = __shfl(cA, 4 * g + 2), c3 = __shfl(cA, 4 * g + 3);
#pragma unroll
      for (int nt = 0; nt < 4; nt++) {
        accA[nt][0] *= c0; accA[nt][1] *= c1;
        accA[nt][2] *= c2; accA[nt][3] *= c3;
      }
      float d0 = __shfl(cB, 4 * g + 0), d1 = __shfl(cB, 4 * g + 1);
      float d2 = __shfl(cB, 4 * g + 2), d3 = __shfl(cB, 4 * g + 3);
#pragma unroll
      for (int nt = 0; nt < 4; nt++) {
        accB[nt][0] *= d0; accB[nt][1] *= d1;
        accB[nt][2] *= d2; accB[nt][3] *= d3;
      }
      lA *= cA; lB *= cB;
      mA = mnA; mB = mnB;
    }

    float psA = 0.f, psB = 0.f;
#define PBLK(SARR, MM, PS, PWP, OFF)                                          \
    {                                                                         \
      float p0 = SARR[0] - MM, p1 = SARR[1] - MM,                             \
            p2 = SARR[2] - MM, p3 = SARR[3] - MM;                             \
      asm volatile("v_exp_f32 %0, %0\n\tv_exp_f32 %1, %1\n\t"                 \
                   "v_exp_f32 %2, %2\n\tv_exp_f32 %3, %3\n\ts_nop 1"          \
                   : "+v"(p0), "+v"(p1), "+v"(p2), "+v"(p3));                 \
      PS += (p0 + p1) + (p2 + p3);                                            \
      uint2 pv;                                                               \
      asm("v_cvt_pk_bf16_f32 %0, %1, %2" : "=v"(pv.x) : "v"(p0), "v"(p1));    \
      asm("v_cvt_pk_bf16_f32 %0, %1, %2" : "=v"(pv.y) : "v"(p2), "v"(p3));    \
      *(uint2*)(PWP + OFF) = pv;                                              \
    }
    // ---- pass 0: keys 0..63 ----
    PBLK(sA[0], mA, psA, pw0, 0) PBLK(sA[1], mA, psA, pw1, 0)
    PBLK(sA[2], mA, psA, pw2, 0) PBLK(sA[3], mA, psA, pw3, 0)
    PBLK(sB[0], mB, psB, pw0, 2048) PBLK(sB[1], mB, psB, pw1, 2048)
    PBLK(sB[2], mB, psB, pw2, 2048) PBLK(sB[3], mB, psB, pw3, 2048)
    {
      bf16x8 paA0 = *(const bf16x8*)(pb0);
      bf16x8 paB0 = *(const bf16x8*)(pb0 + 2048);
#pragma unroll
      for (int nt = 0; nt < 4; nt++) {
        bf16x8 vb = *(const bf16x8*)(base + vrowb + nt * 4096 + vs00);
        accA[nt] = __builtin_amdgcn_mfma_f32_16x16x32_bf16(paA0, vb, accA[nt], 0, 0, 0);
        accB[nt] = __builtin_amdgcn_mfma_f32_16x16x32_bf16(paB0, vb, accB[nt], 0, 0, 0);
      }
      bf16x8 paA1 = *(const bf16x8*)(pb1);
      bf16x8 paB1 = *(const bf16x8*)(pb1 + 2048);
#pragma unroll
      for (int nt = 0; nt < 4; nt++) {
        bf16x8 vb = *(const bf16x8*)(base + vrowb + nt * 4096 + vs01);
        accA[nt] = __builtin_amdgcn_mfma_f32_16x16x32_bf16(paA1, vb, accA[nt], 0, 0, 0);
        accB[nt] = __builtin_amdgcn_mfma_f32_16x16x32_bf16(paB1, vb, accB[nt], 0, 0, 0);
      }
    }
    // ---- pass 1: keys 64..127 (reuse wave-private P buffer) ----
    PBLK(sA[4], mA, psA, pw0, 0) PBLK(sA[5], mA, psA, pw1, 0)
    PBLK(sA[6], mA, psA, pw2, 0) PBLK(sA[7], mA, psA, pw3, 0)
    PBLK(sB[4], mB, psB, pw0, 2048) PBLK(sB[5], mB, psB, pw1, 2048)
    PBLK(sB[6], mB, psB, pw2, 2048) PBLK(sB[7], mB, psB, pw3, 2048)
#undef PBLK
    {
      bf16x8 paA0 = *(const bf16x8*)(pb0);
      bf16x8 paB0 = *(const bf16x8*)(pb0 + 2048);
#pragma unroll
      for (int nt = 0; nt < 4; nt++) {
        bf16x8 vb = *(const bf16x8*)(base + vrowb + nt * 4096 + vs10);
        accA[nt] = __builtin_amdgcn_mfma_f32_16x16x32_bf16(paA0, vb, accA[nt], 0, 0, 0);
        accB[nt] = __builtin_amdgcn_mfma_f32_16x16x32_bf16(paB0, vb, accB[nt], 0, 0, 0);
      }
      bf16x8 paA1 = *(const bf16x8*)(pb1);
      bf16x8 paB1 = *(const bf16x8*)(pb1 + 2048);
#pragma unroll
      for (int nt = 0; nt < 4; nt++) {
        bf16x8 vb = *(const bf16x8*)(base + vrowb + nt * 4096 + vs11);
        accA[nt] = __builtin_amdgcn_mfma_f32_16x16x32_bf16(paA1, vb, accA[nt], 0, 0, 0);
        accB[nt] = __builtin_amdgcn_mfma_f32_16x16x32_bf16(paB1, vb, accB[nt], 0, 0, 0);
      }
    }
    psA += swz16f(psA); psA += __shfl_xor(psA, 32); lA += psA;
    psB += swz16f(psB); psB += __shfl_xor(psB, 32); lB += psB;

    pipe_sync();
  }

  float liA[4], liB[4];
#pragma unroll
  for (int i = 0; i < 4; i++) {
    liA[i] = 1.f / __shfl(lA, 4 * g + i);
    liB[i] = 1.f / __shfl(lB, 4 * g + i);
  }
#pragma unroll
  for (int i = 0; i < 4; i++) {
    size_t ra = (tb + wq + 4 * g + i) * 512 + h * 64;
    size_t rb = (tb + wq + 16 + 4 * g + i) * 512 + h * 64;
#pragma unroll
    for (int nt = 0; nt < 4; nt++) {
      ctx[ra + 16 * nt + li] = f2bf(accA[nt][i] * liA[i]);
      ctx[rb + 16 * nt + li] = f2bf(accB[nt][i] * liB[i]);
    }
  }
}

// ---------------- LayerNorm over E=512; one wave per row; f32 + bf16 out ------
__global__ __launch_bounds__(256) void ln_kernel(
    const float* __restrict__ X, const float* __restrict__ g,
    const float* __restrict__ b, float* __restrict__ Yf,
    unsigned short* __restrict__ Yb)
{
  int t = threadIdx.x, lane = t & 63, wv = t >> 6;
  size_t row = (size_t)blockIdx.x * 4 + wv;
  const float* xp = X + row * 512 + lane * 8;
  float4 a = *(const float4*)xp;
  float4 c = *(const float4*)(xp + 4);
  float sum = a.x + a.y + a.z + a.w + c.x + c.y + c.z + c.w;
  float sq  = a.x*a.x + a.y*a.y + a.z*a.z + a.w*a.w
            + c.x*c.x + c.y*c.y + c.z*c.z + c.w*c.w;
#pragma unroll
  for (int off = 32; off > 0; off >>= 1) {
    sum += __shfl_xor(sum, off);
    sq  += __shfl_xor(sq, off);
  }
  float mu  = sum * (1.0f / 512.0f);
  float inv = rsqrtf(sq * (1.0f / 512.0f) - mu * mu + 1e-5f);
  float4 g0 = *(const float4*)(g + lane * 8);
  float4 g1 = *(const float4*)(g + lane * 8 + 4);
  float4 b0 = *(const float4*)(b + lane * 8);
  float4 b1 = *(const float4*)(b + lane * 8 + 4);
  float y[8];
  y[0] = (a.x - mu) * inv * g0.x + b0.x;
  y[1] = (a.y - mu) * inv * g0.y + b0.y;
  y[2] = (a.z - mu) * inv * g0.z + b0.z;
  y[3] = (a.w - mu) * inv * g0.w + b0.w;
  y[4] = (c.x - mu) * inv * g1.x + b1.x;
  y[5] = (c.y - mu) * inv * g1.y + b1.y;
  y[6] = (c.z - mu) * inv * g1.z + b1.z;
  y[7] = (c.w - mu) * inv * g1.w + b1.w;
  float4 y0 = {y[0], y[1], y[2], y[3]};
  float4 y1 = {y[4], y[5], y[6], y[7]};
  *(float4*)(Yf + row * 512 + lane * 8)     = y0;
  *(float4*)(Yf + row * 512 + lane * 8 + 4) = y1;
  bf16x8 yb;
#pragma unroll
  for (int j = 0; j < 8; j++) yb[j] = (short)f2bf(y[j]);
  *(bf16x8*)(Yb + row * 512 + lane * 8) = yb;
}

// ---------------- final projection: [8192,512] @ [32,512]^T + b ----------------
__global__ __launch_bounds__(256) void outp_kernel(
    const float* __restrict__ X, const float* __restrict__ W,
    const float* __restrict__ bias, float* __restrict__ Y)
{
  __shared__ __align__(16) float Xs[8][516];
  int t = threadIdx.x;
  int r = t >> 5, n = t & 31;
  size_t rowbase = (size_t)blockIdx.x * 8;
  const float* xp = X + (rowbase + r) * 512 + n * 16;
#pragma unroll
  for (int j = 0; j < 4; j++) {
    float4 v = *(const float4*)(xp + j * 4);
    *(float4*)&Xs[r][n * 16 + j * 4] = v;
  }
  __syncthreads();
  float acc = bias[n];
  const float* wp = W + (size_t)n * 512;
#pragma unroll 4
  for (int k0 = 0; k0 < 512; k0 += 4) {
    float4 h4 = *(const float4*)&Xs[r][k0];
    float4 w4 = *(const float4*)(wp + k0);
    acc += h4.x * w4.x + h4.y * w4.y + h4.z * w4.z + h4.w * w4.w;
  }
  Y[(rowbase + r) * 32 + n] = acc;
}

extern "C" void kernel_launch(void* const* d_in, const int* in_sizes, int n_in,
                              void* d_out, int out_size, void* d_ws, size_t ws_size,
                              hipStream_t stream) {
  (void)in_sizes; (void)n_in; (void)out_size; (void)ws_size;
  const float* x      = (const float*)d_in[0];
  const float* conv_w = (const float*)d_in[1];
  const float* conv_b = (const float*)d_in[2];
  const float* qkv_w  = (const float*)d_in[3];
  const float* qkv_b  = (const float*)d_in[4];
  const float* out_w  = (const float*)d_in[5];
  const float* out_b  = (const float*)d_in[6];
  const float* fc1_w  = (const float*)d_in[7];
  const float* fc1_b  = (const float*)d_in[8];
  const float* fc2_w  = (const float*)d_in[9];
  const float* fc2_b  = (const float*)d_in[10];
  const float* ln1_w  = (const float*)d_in[11];
  const float* ln1_b  = (const float*)d_in[12];
  const float* ln2_w  = (const float*)d_in[13];
  const float* ln2_b  = (const float*)d_in[14];
  const float* outp_w = (const float*)d_in[15];
  const float* outp_b = (const float*)d_in[16];
  float* out = (float*)d_out;

  char* p = (char*)d_ws;
  unsigned short* A_bf = (unsigned short*)p;            p += (size_t)8192 * 512 * 2;
  float*          A_f  = (float*)p;                     p += (size_t)8192 * 512 * 4;
  unsigned short* QKV  = (unsigned short*)p;            p += (size_t)8192 * 1536 * 2;
  unsigned short* VT   = (unsigned short*)p;            p += (size_t)32 * 64 * 2048 * 2;
  unsigned short* CTX  = (unsigned short*)p;            p += (size_t)8192 * 512 * 2;
  unsigned short* Wq   = (unsigned short*)p;            p += (size_t)4 * 1536 * 512 * 2;
  unsigned short* Wo   = (unsigned short*)p;            p += (size_t)4 * 512 * 512 * 2;
  unsigned short* W1   = (unsigned short*)p;            p += (size_t)4 * 512 * 512 * 2;
  unsigned short* W2   = (unsigned short*)p;            p += (size_t)4 * 512 * 512 * 2;
  float* D = (float*)QKV;   // aliased: D[8192,512] f32 in QKV region (disjoint lifetime)

  f2bf_kernel<<<3072, 256, 0, stream>>>(qkv_w, Wq, 786432);
  f2bf_kernel<<<1024, 256, 0, stream>>>(out_w, Wo, 262144);
  f2bf_kernel<<<1024, 256, 0, stream>>>(fc1_w, W1, 262144);
  f2bf_kernel<<<1024, 256, 0, stream>>>(fc2_w, W2, 262144);

  conv_pe_kernel<<<1024, 256, 0, stream>>>(x, conv_w, conv_b, A_f, A_bf);

  for (int l = 0; l < 4; l++) {
    gemm_bf<0, 1, 4><<<64 * 12, 256, 0, stream>>>(
        A_bf, Wq + (size_t)l * 1536 * 512, qkv_b + l * 1536, nullptr,
        QKV, nullptr, 1536);
    vtrans_kernel<<<1024, 256, 0, stream>>>(QKV, VT);
    attn_mfma<<<512, 256, 0, stream>>>(QKV, VT, CTX);
    gemm_bf<1, 0, 2><<<64 * 8, 256, 0, stream>>>(
        CTX, Wo + (size_t)l * 512 * 512, out_b + l * 512, A_f,
        nullptr, D, 512);
    ln_kernel<<<2048, 256, 0, stream>>>(D, ln1_w + l * 512, ln1_b + l * 512, A_f, A_bf);
    gemm_bf<2, 0, 2><<<64 * 8, 256, 0, stream>>>(
        A_bf, W1 + (size_t)l * 512 * 512, fc1_b + l * 512, nullptr,
        CTX, nullptr, 512);
    gemm_bf<1, 0, 2><<<64 * 8, 256, 0, stream>>>(
        CTX, W2 + (size_t)l * 512 * 512, fc2_b + l * 512, A_f,
        nullptr, D, 512);
    ln_kernel<<<2048, 256, 0, stream>>>(D, ln2_w + l * 512, ln2_b + l * 512, A_f, A_bf);
  }
  outp_kernel<<<1024, 256, 0, stream>>>(A_f, outp_w, outp_b, out);
}

// Round 9
// 582.240 us; speedup vs baseline: 1.3754x; 1.0802x over previous
//
#include <hip/hip_runtime.h>
#include <hip/hip_bf16.h>
#include <cstddef>

typedef short bf16x8 __attribute__((ext_vector_type(8)));
typedef float f32x4 __attribute__((ext_vector_type(4)));

__device__ __forceinline__ unsigned short f2bf(float x) {
  __hip_bfloat16 h = __float2bfloat16(x);
  unsigned short u; __builtin_memcpy(&u, &h, 2); return u;
}
__device__ __forceinline__ float swz16f(float x) {   // lane ^= 16 (within 32-group)
  int i; __builtin_memcpy(&i, &x, 4);
  i = __builtin_amdgcn_ds_swizzle(i, 0x401F);
  float r; __builtin_memcpy(&r, &i, 4); return r;
}
__device__ __forceinline__ void gload16(const unsigned short* g, unsigned short* l) {
  __builtin_amdgcn_global_load_lds(
      (const __attribute__((address_space(1))) void*)g,
      (__attribute__((address_space(3))) void*)l, 16, 0, 0);
}
__device__ __forceinline__ void pipe_sync() {
  asm volatile("s_waitcnt vmcnt(0)" ::: "memory");
  __builtin_amdgcn_s_barrier();
  __builtin_amdgcn_sched_barrier(0);
}

// ---------------- all weights fp32 -> bf16 (contiguous dst) ----------------
__global__ __launch_bounds__(256) void cvt_all(
    const float* __restrict__ qkv_w, const float* __restrict__ out_w,
    const float* __restrict__ fc1_w, const float* __restrict__ fc2_w,
    const float* __restrict__ outp_w, unsigned short* __restrict__ dst)
{
  int i = blockIdx.x * 256 + threadIdx.x;
  if (i >= 1576960) return;
  const float* src; int off;
  if (i < 786432)       { src = qkv_w;  off = i; }
  else if (i < 1048576) { src = out_w;  off = i - 786432; }
  else if (i < 1310720) { src = fc1_w;  off = i - 1048576; }
  else if (i < 1572864) { src = fc2_w;  off = i - 1310720; }
  else                  { src = outp_w; off = i - 1572864; }
  float4 v = *(const float4*)(src + (size_t)off * 4);
  ushort4 o;
  o.x = f2bf(v.x); o.y = f2bf(v.y); o.z = f2bf(v.z); o.w = f2bf(v.w);
  *(ushort4*)(dst + (size_t)i * 4) = o;
}

// ---------------- conv1d (circular, k=3) + positional embedding ----------------
__global__ __launch_bounds__(256) void conv_pe_kernel(
    const float* __restrict__ x, const float* __restrict__ cw,
    const float* __restrict__ cb,
    float* __restrict__ outf, unsigned short* __restrict__ outb)
{
  const int L = 2048, CIN = 32;
  int b  = blockIdx.x >> 8;
  int l0 = (blockIdx.x & 255) << 3;
  int t  = threadIdx.x;
  __shared__ float xs[10][32];
  for (int idx = t; idx < 320; idx += 256) {
    int rr = idx >> 5, ci = idx & 31;
    int gl = (l0 - 1 + rr + L) & (L - 1);
    xs[rr][ci] = x[((size_t)b * L + gl) * CIN + ci];
  }
  __syncthreads();
  int e0 = t << 1;
  float acc0[8], acc1[8];
  float bb0 = cb[e0], bb1 = cb[e0 + 1];
#pragma unroll
  for (int li = 0; li < 8; li++) { acc0[li] = bb0; acc1[li] = bb1; }
  const float* w0p = cw + (size_t)e0 * 96;
  const float* w1p = w0p + 96;
  for (int ci = 0; ci < 32; ci++) {
#pragma unroll
    for (int kk = 0; kk < 3; kk++) {
      float w0 = w0p[ci * 3 + kk];
      float w1 = w1p[ci * 3 + kk];
#pragma unroll
      for (int li = 0; li < 8; li++) {
        float xv = xs[li + kk][ci];
        acc0[li] += xv * w0;
        acc1[li] += xv * w1;
      }
    }
  }
  float dv = __expf((float)e0 * (-9.210340371976184f / 512.0f));
#pragma unroll
  for (int li = 0; li < 8; li++) {
    int l = l0 + li;
    float arg = (float)l * dv;
    float sv = sinf(arg), cv = cosf(arg);
    float2 o; o.x = acc0[li] + sv; o.y = acc1[li] + cv;
    size_t off = ((size_t)b * L + l) * 512 + e0;
    *(float2*)&outf[off] = o;
    ushort2 ob; ob.x = f2bf(o.x); ob.y = f2bf(o.y);
    *(ushort2*)&outb[off] = ob;
  }
}

// ---------------- bf16 MFMA GEMM, 2-phase pipelined ----------------
// Y[M,N] = X[M,512] @ W[N,512]^T + bias.  Tile 128 x (NFR*32).
// EPI 0: Yb bf16 (QSCALE: cols<512 prescaled).  EPI 1: Yf f32 = +R.
// EPI 2: SiLU->Yb.  EPI 3: Yf f32 (no residual).
template<int EPI, int QSCALE, int NFR>
__global__ __launch_bounds__(256) void gemm_bf(
    const unsigned short* __restrict__ X,
    const unsigned short* __restrict__ W,
    const float* __restrict__ bias,
    const float* __restrict__ R,
    unsigned short* __restrict__ Yb,
    float* __restrict__ Yf,
    int N)
{
  const int K = 512;
  constexpr int BN = NFR * 32;
  constexpr int WB = NFR * 4096;          // W-region bytes per buffer
  constexpr int BUF = 16384 + WB;
  __shared__ __align__(16) char smem[2 * BUF];
  int t = threadIdx.x;
  int lane = t & 63, wv = t >> 6;
  int g = lane >> 4, li = lane & 15;
  int m0 = (blockIdx.x & 63) << 7;
  int n0 = (blockIdx.x >> 6) * BN;
  int wm = (wv >> 1) << 6;
  int wn = (wv & 1) * (BN / 2);

  int subrow = lane >> 3;
  int coloff = ((lane & 7) ^ subrow) << 3;   // inverse swizzle on global source

  f32x4 acc[4][NFR];
#pragma unroll
  for (int a = 0; a < 4; a++)
#pragma unroll
    for (int b2 = 0; b2 < NFR; b2++) acc[a][b2] = (f32x4){0.f, 0.f, 0.f, 0.f};

  // prologue: stage k-step 0 into buf 0
#pragma unroll
  for (int j = 0; j < 4; j++) {
    int row = (wv * 4 + j) * 8 + subrow;
    gload16(X + (size_t)(m0 + row) * K + coloff,
            (unsigned short*)(smem + (wv * 4 + j) * 1024));
  }
#pragma unroll
  for (int j = 0; j < NFR; j++) {
    int row = (wv * NFR + j) * 8 + subrow;
    gload16(W + (size_t)(n0 + row) * K + coloff,
            (unsigned short*)(smem + 16384 + (wv * NFR + j) * 1024));
  }
  pipe_sync();

#pragma unroll
  for (int ks = 0; ks < 8; ks++) {
    const int buf = ks & 1;
    char* cur = smem + buf * BUF;
    if (ks < 7) {                     // issue next-tile loads first
      char* nxt = smem + (buf ^ 1) * BUF;
      int k0 = (ks + 1) * 64;
#pragma unroll
      for (int j = 0; j < 4; j++) {
        int row = (wv * 4 + j) * 8 + subrow;
        gload16(X + (size_t)(m0 + row) * K + k0 + coloff,
                (unsigned short*)(nxt + (wv * 4 + j) * 1024));
      }
#pragma unroll
      for (int j = 0; j < NFR; j++) {
        int row = (wv * NFR + j) * 8 + subrow;
        gload16(W + (size_t)(n0 + row) * K + k0 + coloff,
                (unsigned short*)(nxt + 16384 + (wv * NFR + j) * 1024));
      }
    }
#pragma unroll
    for (int s = 0; s < 2; s++) {
      bf16x8 af[4], bfr[NFR];
#pragma unroll
      for (int mt = 0; mt < 4; mt++) {
        int row = wm + 16 * mt + li;
        af[mt] = *(const bf16x8*)(cur + (row * 8 + ((g + 4 * s) ^ (row & 7))) * 16);
      }
#pragma unroll
      for (int nt = 0; nt < NFR; nt++) {
        int row = wn + 16 * nt + li;
        bfr[nt] = *(const bf16x8*)(cur + 16384 +
                                   (row * 8 + ((g + 4 * s) ^ (row & 7))) * 16);
      }
#pragma unroll
      for (int mt = 0; mt < 4; mt++)
#pragma unroll
        for (int nt = 0; nt < NFR; nt++)
          acc[mt][nt] = __builtin_amdgcn_mfma_f32_16x16x32_bf16(
              af[mt], bfr[nt], acc[mt][nt], 0, 0, 0);
    }
    pipe_sync();
  }

  float bv[NFR];
#pragma unroll
  for (int nt = 0; nt < NFR; nt++) bv[nt] = bias[n0 + wn + 16 * nt + li];
#pragma unroll
  for (int mt = 0; mt < 4; mt++) {
#pragma unroll
    for (int i = 0; i < 4; i++) {
      size_t roff = (size_t)(m0 + wm + 16 * mt + 4 * g + i) * N;
#pragma unroll
      for (int nt = 0; nt < NFR; nt++) {
        int col = n0 + wn + 16 * nt + li;
        float v = acc[mt][nt][i] + bv[nt];
        if (EPI == 1) {
          v += R[roff + col];
          Yf[roff + col] = v;
        } else if (EPI == 2) {
          v = v / (1.f + __expf(-v));
          Yb[roff + col] = f2bf(v);
        } else if (EPI == 3) {
          Yf[roff + col] = v;
        } else {
          if (QSCALE && col < 512) v *= 0.18033688011112042f;  // 0.125*log2(e)
          Yb[roff + col] = f2bf(v);
        }
      }
    }
  }
}

// ---------------- V transpose: qkv_bf V-part -> Vt[32][64][2048] ----------------
__global__ __launch_bounds__(256) void vtrans_kernel(
    const unsigned short* __restrict__ qkv, unsigned short* __restrict__ Vt)
{
  int ki = blockIdx.x & 31, bh = blockIdx.x >> 5;
  int b = bh >> 3, h = bh & 7;
  int kt = ki << 6;
  __shared__ unsigned short T[64][72];
  int t = threadIdx.x;
  int r = t >> 2, c0 = (t & 3) << 4;
  const unsigned short* src =
      qkv + ((size_t)(b * 2048 + kt + r)) * 1536 + 1024 + h * 64 + c0;
  bf16x8 a0 = *(const bf16x8*)src;
  bf16x8 a1 = *(const bf16x8*)(src + 8);
  *(bf16x8*)&T[r][c0] = a0;
  *(bf16x8*)&T[r][c0 + 8] = a1;
  __syncthreads();
  int d = t >> 2, k0 = (t & 3) << 4;
  bf16x8 v0, v1;
#pragma unroll
  for (int j = 0; j < 8; j++) v0[j] = (short)T[k0 + j][d];
#pragma unroll
  for (int j = 0; j < 8; j++) v1[j] = (short)T[k0 + 8 + j][d];
  unsigned short* dst = Vt + ((size_t)bh * 64 + d) * 2048 + kt + k0;
  *(bf16x8*)dst = v0;
  *(bf16x8*)(dst + 8) = v1;
}

// ---------------- MFMA flash attention, 2-phase pipelined, KVBLK=128 ----------
// QBLK=128; grid 512: bh = bid&31 (XCD-local), qi = bid>>5; 4 waves; Q prescaled.
__global__ __launch_bounds__(256) void attn_mfma(
    const unsigned short* __restrict__ qkv,  // [8192,1536] bf16
    const unsigned short* __restrict__ Vt,   // [32,64,2048] bf16
    unsigned short* __restrict__ ctx)        // [8192,512] bf16
{
  const int L = 2048;
  int bh = blockIdx.x & 31, qi = blockIdx.x >> 5;   // same-bh blocks -> same XCD
  int b = bh >> 3, h = bh & 7;
  int q0 = qi << 7;
  size_t tb = (size_t)b * L;
  int t = threadIdx.x, lane = t & 63, wv = t >> 6;
  int g = lane >> 4, li = lane & 15;
  int lisw = li & 7;

  // smem: buf{0,1}: [K 16K | V 16K] at 0/32768 ; P 16K at 65536 (4K/wave)
  __shared__ __align__(16) char smem[81920];

  int wq = q0 + wv * 32;
  bf16x8 qf00, qf01, qf10, qf11;
  {
    const unsigned short* qp0 = qkv + (tb + wq + li) * 1536 + h * 64 + g * 8;
    qf00 = *(const bf16x8*)qp0;
    qf01 = *(const bf16x8*)(qp0 + 32);
    const unsigned short* qp1 = qp0 + (size_t)16 * 1536;
    qf10 = *(const bf16x8*)qp1;
    qf11 = *(const bf16x8*)(qp1 + 32);
  }

  f32x4 accA[4], accB[4];
#pragma unroll
  for (int nt = 0; nt < 4; nt++) {
    accA[nt] = (f32x4){0.f, 0.f, 0.f, 0.f};
    accB[nt] = (f32x4){0.f, 0.f, 0.f, 0.f};
  }
  float mA = -1e30f, mB = -1e30f, lA = 0.f, lB = 0.f;

  // K fragment offsets (K region rows = 128B): row = 16mt+li
  int koff0 = li * 128 + ((g    ) ^ lisw) * 16;
  int koff1 = li * 128 + ((g + 4) ^ lisw) * 16;
  // V fragment offsets (V region rows = 256B, 16 slots): row = 16nt+li
  int vrowb = 16384 + li * 256;
  int vs00 = ((g    ) ^ lisw) << 4;     // pass 0, d-half 0
  int vs01 = ((g + 4) ^ lisw) << 4;     // pass 0, d-half 1
  int vs10 = ((8 + g) ^ lisw) << 4;     // pass 1, d-half 0
  int vs11 = ((12 + g) ^ lisw) << 4;    // pass 1, d-half 1
  // P pointers (wave-private 4KB at 65536)
  const char* pb0 = smem + 65536 + wv * 4096 + li * 128 + ((g    ) ^ lisw) * 16;
  const char* pb1 = smem + 65536 + wv * 4096 + li * 128 + ((g + 4) ^ lisw) * 16;
  char* pwbase = smem + 65536 + wv * 4096 + li * 128 + ((g & 1) << 3);
  char* pw0 = pwbase + (((0 + (g >> 1)) ^ lisw) << 4);
  char* pw1 = pwbase + (((2 + (g >> 1)) ^ lisw) << 4);
  char* pw2 = pwbase + (((4 + (g >> 1)) ^ lisw) << 4);
  char* pw3 = pwbase + (((6 + (g >> 1)) ^ lisw) << 4);

  // staging pointers: K 4 issues (rows 0..127), V 4 issues (rows 0..63)
  int subrow = lane >> 3;
  int coloff = ((lane & 7) ^ subrow) << 3;
  const unsigned short* kp[4];
  const unsigned short* vp[4];
#pragma unroll
  for (int j = 0; j < 4; j++) {
    int krow = (wv * 4 + j) * 8 + subrow;
    kp[j] = qkv + (tb + krow) * 1536 + 512 + h * 64 + coloff;
    int vrow = (wv * 4 + j) * 4 + g;
    vp[j] = Vt + ((size_t)bh * 64 + vrow) * 2048 + ((li ^ (vrow & 7)) << 3);
  }

  // prologue: stage tile 0 into buf 0
#pragma unroll
  for (int j = 0; j < 4; j++) {
    gload16(kp[j], (unsigned short*)(smem + (wv * 4 + j) * 1024));
    gload16(vp[j], (unsigned short*)(smem + 16384 + (wv * 4 + j) * 1024));
    kp[j] += (size_t)128 * 1536; vp[j] += 128;
  }
  pipe_sync();

#pragma unroll 2
  for (int it = 0; it < 16; it++) {
    const int buf = it & 1;
    const char* base = smem + buf * 32768;
    if (it < 15) {                    // issue next tile first (latency hides)
      char* nb = smem + (buf ^ 1) * 32768;
#pragma unroll
      for (int j = 0; j < 4; j++) {
        gload16(kp[j], (unsigned short*)(nb + (wv * 4 + j) * 1024));
        gload16(vp[j], (unsigned short*)(nb + 16384 + (wv * 4 + j) * 1024));
        kp[j] += (size_t)128 * 1536; vp[j] += 128;
      }
    }

    // S^T = K . Q^T over 128 keys (8 fragments per d-half)
    f32x4 sA[8], sB[8];
#pragma unroll
    for (int mt = 0; mt < 8; mt++) {
      sA[mt] = (f32x4){0.f, 0.f, 0.f, 0.f};
      sB[mt] = (f32x4){0.f, 0.f, 0.f, 0.f};
    }
    __builtin_amdgcn_s_setprio(1);
#pragma unroll
    for (int mt = 0; mt < 8; mt++) {
      bf16x8 kf = *(const bf16x8*)(base + koff0 + mt * 2048);
      sA[mt] = __builtin_amdgcn_mfma_f32_16x16x32_bf16(kf, qf00, sA[mt], 0, 0, 0);
      sB[mt] = __builtin_amdgcn_mfma_f32_16x16x32_bf16(kf, qf10, sB[mt], 0, 0, 0);
    }
#pragma unroll
    for (int mt = 0; mt < 8; mt++) {
      bf16x8 kf = *(const bf16x8*)(base + koff1 + mt * 2048);
      sA[mt] = __builtin_amdgcn_mfma_f32_16x16x32_bf16(kf, qf01, sA[mt], 0, 0, 0);
      sB[mt] = __builtin_amdgcn_mfma_f32_16x16x32_bf16(kf, qf11, sB[mt], 0, 0, 0);
    }
    __builtin_amdgcn_s_setprio(0);

    // tile maxes over 128 keys
    float mxA = -1e30f, mxB = -1e30f;
#pragma unroll
    for (int mt = 0; mt < 8; mt++) {
      mxA = fmaxf(mxA, fmaxf(fmaxf(sA[mt][0], sA[mt][1]), fmaxf(sA[mt][2], sA[mt][3])));
      mxB = fmaxf(mxB, fmaxf(fmaxf(sB[mt][0], sB[mt][1]), fmaxf(sB[mt][2], sB[mt][3])));
    }
    mxA = fmaxf(mxA, swz16f(mxA)); mxA = fmaxf(mxA, __shfl_xor(mxA, 32));
    mxB = fmaxf(mxB, swz16f(mxB)); mxB = fmaxf(mxB, __shfl_xor(mxB, 32));

    // defer-max (THR=8, exp2 domain)
    if (__any((mxA > mA + 8.0f) || (mxB > mB + 8.0f))) {
      float mnA = fmaxf(mA, mxA), mnB = fmaxf(mB, mxB);
      float cA = mA - mnA, cB = mB - mnB;
      asm volatile("v_exp_f32 %0, %0\n\tv_exp_f32 %1, %1\n\ts_nop 1"
                   : "+v"(cA), "+v"(cB));
      float c0 = __shfl(cA, 4 * g + 0), c1 = __shfl(cA, 4 * g + 1);
      float c2 = __shfl(cA, 4 * g + 2), c3 = __shfl(cA, 4 * g + 3);
#pragma unroll
      for (int nt = 0; nt < 4; nt++) {
        accA[nt][0] *= c0; accA[nt][1] *= c1;
        accA[nt][2] *= c2; accA[nt][3] *= c3;
      }
      float d0 = __shfl(cB, 4 * g + 0), d1 = __shfl(cB, 4 * g + 1);
      float d2 = __shfl(cB, 4 * g + 2), d3 = __shfl(cB, 4 * g + 3);
#pragma unroll
      for (int nt = 0; nt < 4; nt++) {
        accB[nt][0] *= d0; accB[nt][1] *= d1;
        accB[nt][2] *= d2; accB[nt][3] *= d3;
      }
      lA *= cA; lB *= cB;
      mA = mnA; mB = mnB;
    }

    float psA = 0.f, psB = 0.f;
#define PBLK(SARR, MM, PS, PWP, OFF)                                          \
    {                                                                         \
      float p0 = SARR[0] - MM, p1 = SARR[1] - MM,                             \
            p2 = SARR[2] - MM, p3 = SARR[3] - MM;                             \
      asm volatile("v_exp_f32 %0, %0\n\tv_exp_f32 %1, %1\n\t"                 \
                   "v_exp_f32 %2, %2\n\tv_exp_f32 %3, %3\n\ts_nop 1"          \
                   : "+v"(p0), "+v"(p1), "+v"(p2), "+v"(p3));                 \
      PS += (p0 + p1) + (p2 + p3);                                            \
      uint2 pv;                                                               \
      asm("v_cvt_pk_bf16_f32 %0, %1, %2" : "=v"(pv.x) : "v"(p0), "v"(p1));    \
      asm("v_cvt_pk_bf16_f32 %0, %1, %2" : "=v"(pv.y) : "v"(p2), "v"(p3));    \
      *(uint2*)(PWP + OFF) = pv;                                              \
    }
    // ---- pass 0: keys 0..63 ----
    PBLK(sA[0], mA, psA, pw0, 0) PBLK(sA[1], mA, psA, pw1, 0)
    PBLK(sA[2], mA, psA, pw2, 0) PBLK(sA[3], mA, psA, pw3, 0)
    PBLK(sB[0], mB, psB, pw0, 2048) PBLK(sB[1], mB, psB, pw1, 2048)
    PBLK(sB[2], mB, psB, pw2, 2048) PBLK(sB[3], mB, psB, pw3, 2048)
    {
      bf16x8 paA0 = *(const bf16x8*)(pb0);
      bf16x8 paB0 = *(const bf16x8*)(pb0 + 2048);
      __builtin_amdgcn_s_setprio(1);
#pragma unroll
      for (int nt = 0; nt < 4; nt++) {
        bf16x8 vb = *(const bf16x8*)(base + vrowb + nt * 4096 + vs00);
        accA[nt] = __builtin_amdgcn_mfma_f32_16x16x32_bf16(paA0, vb, accA[nt], 0, 0, 0);
        accB[nt] = __builtin_amdgcn_mfma_f32_16x16x32_bf16(paB0, vb, accB[nt], 0, 0, 0);
      }
      __builtin_amdgcn_s_setprio(0);
      bf16x8 paA1 = *(const bf16x8*)(pb1);
      bf16x8 paB1 = *(const bf16x8*)(pb1 + 2048);
      __builtin_amdgcn_s_setprio(1);
#pragma unroll
      for (int nt = 0; nt < 4; nt++) {
        bf16x8 vb = *(const bf16x8*)(base + vrowb + nt * 4096 + vs01);
        accA[nt] = __builtin_amdgcn_mfma_f32_16x16x32_bf16(paA1, vb, accA[nt], 0, 0, 0);
        accB[nt] = __builtin_amdgcn_mfma_f32_16x16x32_bf16(paB1, vb, accB[nt], 0, 0, 0);
      }
      __builtin_amdgcn_s_setprio(0);
    }
    // ---- pass 1: keys 64..127 (reuse wave-private P buffer) ----
    PBLK(sA[4], mA, psA, pw0, 0) PBLK(sA[5], mA, psA, pw1, 0)
    PBLK(sA[6], mA, psA, pw2, 0) PBLK(sA[7], mA, psA, pw3, 0)
    PBLK(sB[4], mB, psB, pw0, 2048) PBLK(sB[5], mB, psB, pw1, 2048)
    PBLK(sB[6], mB, psB, pw2, 2048) PBLK(sB[7], mB, psB, pw3, 2048)
#undef PBLK
    {
      bf16x8 paA0 = *(const bf16x8*)(pb0);
      bf16x8 paB0 = *(const bf16x8*)(pb0 + 2048);
      __builtin_amdgcn_s_setprio(1);
#pragma unroll
      for (int nt = 0; nt < 4; nt++) {
        bf16x8 vb = *(const bf16x8*)(base + vrowb + nt * 4096 + vs10);
        accA[nt] = __builtin_amdgcn_mfma_f32_16x16x32_bf16(paA0, vb, accA[nt], 0, 0, 0);
        accB[nt] = __builtin_amdgcn_mfma_f32_16x16x32_bf16(paB0, vb, accB[nt], 0, 0, 0);
      }
      __builtin_amdgcn_s_setprio(0);
      bf16x8 paA1 = *(const bf16x8*)(pb1);
      bf16x8 paB1 = *(const bf16x8*)(pb1 + 2048);
      __builtin_amdgcn_s_setprio(1);
#pragma unroll
      for (int nt = 0; nt < 4; nt++) {
        bf16x8 vb = *(const bf16x8*)(base + vrowb + nt * 4096 + vs11);
        accA[nt] = __builtin_amdgcn_mfma_f32_16x16x32_bf16(paA1, vb, accA[nt], 0, 0, 0);
        accB[nt] = __builtin_amdgcn_mfma_f32_16x16x32_bf16(paB1, vb, accB[nt], 0, 0, 0);
      }
      __builtin_amdgcn_s_setprio(0);
    }
    psA += swz16f(psA); psA += __shfl_xor(psA, 32); lA += psA;
    psB += swz16f(psB); psB += __shfl_xor(psB, 32); lB += psB;

    pipe_sync();
  }

  float liA[4], liB[4];
#pragma unroll
  for (int i = 0; i < 4; i++) {
    liA[i] = 1.f / __shfl(lA, 4 * g + i);
    liB[i] = 1.f / __shfl(lB, 4 * g + i);
  }
#pragma unroll
  for (int i = 0; i < 4; i++) {
    size_t ra = (tb + wq + 4 * g + i) * 512 + h * 64;
    size_t rb = (tb + wq + 16 + 4 * g + i) * 512 + h * 64;
#pragma unroll
    for (int nt = 0; nt < 4; nt++) {
      ctx[ra + 16 * nt + li] = f2bf(accA[nt][i] * liA[i]);
      ctx[rb + 16 * nt + li] = f2bf(accB[nt][i] * liB[i]);
    }
  }
}

// ---------------- LayerNorm over E=512; one wave per row; f32 + bf16 out ------
__global__ __launch_bounds__(256) void ln_kernel(
    const float* __restrict__ X, const float* __restrict__ g,
    const float* __restrict__ b, float* __restrict__ Yf,
    unsigned short* __restrict__ Yb)
{
  int t = threadIdx.x, lane = t & 63, wv = t >> 6;
  size_t row = (size_t)blockIdx.x * 4 + wv;
  const float* xp = X + row * 512 + lane * 8;
  float4 a = *(const float4*)xp;
  float4 c = *(const float4*)(xp + 4);
  float sum = a.x + a.y + a.z + a.w + c.x + c.y + c.z + c.w;
  float sq  = a.x*a.x + a.y*a.y + a.z*a.z + a.w*a.w
            + c.x*c.x + c.y*c.y + c.z*c.z + c.w*c.w;
#pragma unroll
  for (int off = 32; off > 0; off >>= 1) {
    sum += __shfl_xor(sum, off);
    sq  += __shfl_xor(sq, off);
  }
  float mu  = sum * (1.0f / 512.0f);
  float inv = rsqrtf(sq * (1.0f / 512.0f) - mu * mu + 1e-5f);
  float4 g0 = *(const float4*)(g + lane * 8);
  float4 g1 = *(const float4*)(g + lane * 8 + 4);
  float4 b0 = *(const float4*)(b + lane * 8);
  float4 b1 = *(const float4*)(b + lane * 8 + 4);
  float y[8];
  y[0] = (a.x - mu) * inv * g0.x + b0.x;
  y[1] = (a.y - mu) * inv * g0.y + b0.y;
  y[2] = (a.z - mu) * inv * g0.z + b0.z;
  y[3] = (a.w - mu) * inv * g0.w + b0.w;
  y[4] = (c.x - mu) * inv * g1.x + b1.x;
  y[5] = (c.y - mu) * inv * g1.y + b1.y;
  y[6] = (c.z - mu) * inv * g1.z + b1.z;
  y[7] = (c.w - mu) * inv * g1.w + b1.w;
  float4 y0 = {y[0], y[1], y[2], y[3]};
  float4 y1 = {y[4], y[5], y[6], y[7]};
  *(float4*)(Yf + row * 512 + lane * 8)     = y0;
  *(float4*)(Yf + row * 512 + lane * 8 + 4) = y1;
  bf16x8 yb;
#pragma unroll
  for (int j = 0; j < 8; j++) yb[j] = (short)f2bf(y[j]);
  *(bf16x8*)(Yb + row * 512 + lane * 8) = yb;
}

extern "C" void kernel_launch(void* const* d_in, const int* in_sizes, int n_in,
                              void* d_out, int out_size, void* d_ws, size_t ws_size,
                              hipStream_t stream) {
  (void)in_sizes; (void)n_in; (void)out_size; (void)ws_size;
  const float* x      = (const float*)d_in[0];
  const float* conv_w = (const float*)d_in[1];
  const float* conv_b = (const float*)d_in[2];
  const float* qkv_w  = (const float*)d_in[3];
  const float* qkv_b  = (const float*)d_in[4];
  const float* out_w  = (const float*)d_in[5];
  const float* out_b  = (const float*)d_in[6];
  const float* fc1_w  = (const float*)d_in[7];
  const float* fc1_b  = (const float*)d_in[8];
  const float* fc2_w  = (const float*)d_in[9];
  const float* fc2_b  = (const float*)d_in[10];
  const float* ln1_w  = (const float*)d_in[11];
  const float* ln1_b  = (const float*)d_in[12];
  const float* ln2_w  = (const float*)d_in[13];
  const float* ln2_b  = (const float*)d_in[14];
  const float* outp_w = (const float*)d_in[15];
  const float* outp_b = (const float*)d_in[16];
  float* out = (float*)d_out;

  char* p = (char*)d_ws;
  unsigned short* A_bf = (unsigned short*)p;            p += (size_t)8192 * 512 * 2;
  float*          A_f  = (float*)p;                     p += (size_t)8192 * 512 * 4;
  unsigned short* QKV  = (unsigned short*)p;            p += (size_t)8192 * 1536 * 2;
  unsigned short* VT   = (unsigned short*)p;            p += (size_t)32 * 64 * 2048 * 2;
  unsigned short* CTX  = (unsigned short*)p;            p += (size_t)8192 * 512 * 2;
  unsigned short* Wq   = (unsigned short*)p;            p += (size_t)4 * 1536 * 512 * 2;
  unsigned short* Wo   = (unsigned short*)p;            p += (size_t)4 * 512 * 512 * 2;
  unsigned short* W1   = (unsigned short*)p;            p += (size_t)4 * 512 * 512 * 2;
  unsigned short* W2   = (unsigned short*)p;            p += (size_t)4 * 512 * 512 * 2;
  unsigned short* Wp   = (unsigned short*)p;            p += (size_t)32 * 512 * 2;
  float* D = (float*)QKV;   // aliased: D[8192,512] f32 in QKV region (disjoint lifetime)

  cvt_all<<<6160, 256, 0, stream>>>(qkv_w, out_w, fc1_w, fc2_w, outp_w, Wq);

  conv_pe_kernel<<<1024, 256, 0, stream>>>(x, conv_w, conv_b, A_f, A_bf);

  for (int l = 0; l < 4; l++) {
    gemm_bf<0, 1, 4><<<64 * 12, 256, 0, stream>>>(
        A_bf, Wq + (size_t)l * 1536 * 512, qkv_b + l * 1536, nullptr,
        QKV, nullptr, 1536);
    vtrans_kernel<<<1024, 256, 0, stream>>>(QKV, VT);
    attn_mfma<<<512, 256, 0, stream>>>(QKV, VT, CTX);
    gemm_bf<1, 0, 2><<<64 * 8, 256, 0, stream>>>(
        CTX, Wo + (size_t)l * 512 * 512, out_b + l * 512, A_f,
        nullptr, D, 512);
    ln_kernel<<<2048, 256, 0, stream>>>(D, ln1_w + l * 512, ln1_b + l * 512, A_f, A_bf);
    gemm_bf<2, 0, 2><<<64 * 8, 256, 0, stream>>>(
        A_bf, W1 + (size_t)l * 512 * 512, fc1_b + l * 512, nullptr,
        CTX, nullptr, 512);
    gemm_bf<1, 0, 2><<<64 * 8, 256, 0, stream>>>(
        CTX, W2 + (size_t)l * 512 * 512, fc2_b + l * 512, A_f,
        nullptr, D, 512);
    ln_kernel<<<2048, 256, 0, stream>>>(D, ln2_w + l * 512, ln2_b + l * 512, A_f, A_bf);
  }
  gemm_bf<3, 0, 1><<<64, 256, 0, stream>>>(
      A_bf, Wp, outp_b, nullptr, nullptr, out, 32);
}